// Round 7
// baseline (7964.200 us; speedup 1.0000x reference)
//
#include <hip/hip_runtime.h>
#include <stdint.h>

#define TSN 400
#define NB 16
#define HENC 512
#define HD2 1024
#define G3E 1536
#define G3D 3072
#define EMBD 300
#define AEMB 32
#define NV 50000
#define NEXT 50100
#define NVP 50176
#define NTT 32
#define NEG_INF (-1.0e12f)

typedef __attribute__((ext_vector_type(8))) short bf16x8;
typedef __attribute__((ext_vector_type(4))) float f32x4;

__device__ __forceinline__ ushort f2bf(float f) {
  unsigned u = __float_as_uint(f);
  unsigned r = (u + 0x7fffu + ((u >> 16) & 1u)) >> 16;
  return (ushort)r;
}
__device__ __forceinline__ float bf2f(ushort h) {
  return __uint_as_float((unsigned)h << 16);
}
__device__ __forceinline__ unsigned agat_ld(const unsigned* p) {
  return __hip_atomic_load(p, __ATOMIC_RELAXED, __HIP_MEMORY_SCOPE_AGENT);
}
__device__ __forceinline__ void agat_st(unsigned* p, unsigned v) {
  __hip_atomic_store(p, v, __ATOMIC_RELAXED, __HIP_MEMORY_SCOPE_AGENT);
}
__device__ __forceinline__ bf16x8 ld8a(const ushort* p) {
  const unsigned* u = (const unsigned*)p;
  union { unsigned d[4]; bf16x8 h; } c;
  c.d[0] = agat_ld(u); c.d[1] = agat_ld(u + 1);
  c.d[2] = agat_ld(u + 2); c.d[3] = agat_ld(u + 3);
  return c.h;
}
// drain stores to coherence point, then padded-slot grid barrier (fence-free)
__device__ __forceinline__ void pbar(int* slots, int nb, int bid, int tid, int e) {
  asm volatile("s_waitcnt vmcnt(0)" ::: "memory");
  __syncthreads();
  if (tid == 0) agat_st((unsigned*)(slots + bid*32), (unsigned)e);
  if (tid < nb) {
    while ((int)agat_ld((const unsigned*)(slots + tid*32)) < e)
      __builtin_amdgcn_s_sleep(1);
  }
  __syncthreads();
}

// ---------------- embeddings -> bf16, padded K=384 ----------------
__global__ __launch_bounds__(256) void k_embed_bf(
    const float* __restrict__ enc_emb, const float* __restrict__ ans_emb,
    const int* __restrict__ input_s, const int* __restrict__ input_a,
    ushort* __restrict__ X0)
{
  long i = (long)blockIdx.x*256 + threadIdx.x;
  if (i >= (long)TSN*NB*384) return;
  int c = (int)(i % 384);
  long r = i / 384;
  int b = (int)(r % NB);
  int t = (int)(r / NB);
  float v = 0.f;
  if (c < EMBD) v = enc_emb[(long)input_s[b*TSN + t]*EMBD + c];
  else if (c < 332) v = ans_emb[(long)input_a[b*TSN + t]*AEMB + (c - EMBD)];
  X0[i] = f2bf(v);
}

// ---------------- decoder emb -> bf16, padded K=320 ----------------
__global__ __launch_bounds__(256) void k_embq_bf(
    const float* __restrict__ dec_emb, const int* __restrict__ input_q,
    ushort* __restrict__ EQ)
{
  long i = (long)blockIdx.x*256 + threadIdx.x;
  if (i >= (long)NTT*NB*320) return;
  int c = (int)(i % 320);
  long r = i / 320;
  int b = (int)(r % NB);
  int s = (int)(r / NB);
  EQ[i] = (c < EMBD) ? f2bf(dec_emb[(long)input_q[b*33 + s]*EMBD + c]) : (ushort)0;
}

// ---------------- weight cast with pad ----------------
__global__ __launch_bounds__(256) void k_castw(
    const float* __restrict__ src, ushort* __restrict__ dst,
    int Nsrc, long total, int Ksrc, int Kdst, int ldsrc, int coloff)
{
  long i = (long)blockIdx.x*256 + threadIdx.x;
  if (i >= total) return;
  int k = (int)(i % Kdst);
  long n = i / Kdst;
  float v = (n < Nsrc && k < Ksrc) ? src[n*ldsrc + coloff + k] : 0.f;
  dst[i] = f2bf(v);
}

// ---------------- plain cast fp32 -> bf16 ----------------
__global__ __launch_bounds__(256) void k_cast(
    const float* __restrict__ s, ushort* __restrict__ d, long n)
{
  long i = (long)blockIdx.x*256 + threadIdx.x;
  if (i >= n) return;
  d[i] = f2bf(s[i]);
}

// ---------------- bf16 batched transpose with K-pad: out[b][c][r(448)] ----------------
__global__ __launch_bounds__(256) void k_transpose_hh(
    const ushort* __restrict__ in, ushort* __restrict__ out)
{
  __shared__ ushort tb[32][33];
  int b = blockIdx.z;
  int r0 = blockIdx.x*32, c0 = blockIdx.y*32;
  int tx = threadIdx.x & 31, ty = threadIdx.x >> 5;
  #pragma unroll
  for (int i = 0; i < 32; i += 8) {
    int r = r0 + ty + i, c = c0 + tx;
    tb[ty+i][tx] = (r < TSN) ? in[((long)b*TSN + r)*1024 + c] : (ushort)0;
  }
  __syncthreads();
  #pragma unroll
  for (int i = 0; i < 32; i += 8) {
    int c = c0 + ty + i, r = r0 + tx;
    out[((long)b*1024 + c)*448 + r] = tb[tx][ty+i];
  }
}

// ---------------- MFMA GEMM ----------------
__global__ __launch_bounds__(256) void k_mfma_nt(
    const ushort* __restrict__ Ab, const ushort* __restrict__ Wb,
    const float* __restrict__ bias, float* __restrict__ Cb, ushort* __restrict__ C2b,
    int M, int N, int K, int lda, int ldw, int ldc,
    long sA, long sW, long sC, long sBias, int accum, int act)
{
  __shared__ ushort As[64][72];
  __shared__ ushort Ws[64][72];
  const ushort* A = Ab + (long)blockIdx.z * sA;
  const ushort* W = Wb + (long)blockIdx.z * sW;
  float* C = Cb + (long)blockIdx.z * sC;
  const float* bi = bias ? bias + (long)blockIdx.z * sBias : nullptr;
  const int m0 = blockIdx.x*64, n0 = blockIdx.y*64;
  const int tid = threadIdx.x;
  const int wave = tid >> 6, lane = tid & 63;
  const int wm = wave >> 1, wn = wave & 1;
  const int lr = lane & 15, kg = lane >> 4;
  f32x4 acc[2][2] = {};
  for (int k0 = 0; k0 < K; k0 += 64) {
    __syncthreads();
    #pragma unroll
    for (int it = 0; it < 2; ++it) {
      int sidx = tid + it*256;
      int r = sidx >> 3, c = (sidx & 7)*8;
      bf16x8 av = {};
      bf16x8 wv = {};
      if (m0 + r < M) av = *(const bf16x8*)&A[(long)(m0+r)*lda + k0 + c];
      if (n0 + r < N) wv = *(const bf16x8*)&W[(long)(n0+r)*ldw + k0 + c];
      *(bf16x8*)&As[r][c] = av;
      *(bf16x8*)&Ws[r][c] = wv;
    }
    __syncthreads();
    #pragma unroll
    for (int kk = 0; kk < 2; ++kk) {
      bf16x8 af[2], bf[2];
      #pragma unroll
      for (int mt = 0; mt < 2; ++mt)
        af[mt] = *(const bf16x8*)&As[wm*32 + mt*16 + lr][kk*32 + kg*8];
      #pragma unroll
      for (int nt = 0; nt < 2; ++nt)
        bf[nt] = *(const bf16x8*)&Ws[wn*32 + nt*16 + lr][kk*32 + kg*8];
      #pragma unroll
      for (int mt = 0; mt < 2; ++mt)
        #pragma unroll
        for (int nt = 0; nt < 2; ++nt)
          acc[mt][nt] = __builtin_amdgcn_mfma_f32_16x16x32_bf16(af[mt], bf[nt], acc[mt][nt], 0, 0, 0);
    }
  }
  #pragma unroll
  for (int mt = 0; mt < 2; ++mt) {
    #pragma unroll
    for (int r = 0; r < 4; ++r) {
      int m = m0 + wm*32 + mt*16 + kg*4 + r;
      if (m >= M) continue;
      #pragma unroll
      for (int nt = 0; nt < 2; ++nt) {
        int n = n0 + wn*32 + nt*16 + lr;
        if (n >= N) continue;
        float v = acc[mt][nt][r];
        if (accum) v += C[(long)m*ldc + n];
        if (bi)    v += bi[n];
        if (act == 1) v = tanhf(v);
        else if (act == 2) v = 1.f/(1.f + expf(-v));
        C[(long)m*ldc + n] = v;
        if (C2b) C2b[(long)blockIdx.z*sC + (long)m*ldc + n] = f2bf(v);
      }
    }
  }
}

// ---------------- persistent MFMA bidirectional GRU scan v4 (proven) ----------------
__global__ __launch_bounds__(256, 1) void k_scan_mfma(
    const float* __restrict__ GXf, const float* __restrict__ GXb,
    const ushort* __restrict__ Whb,
    const float* __restrict__ bh,
    ushort* __restrict__ Ybf, int bmajor,
    float* __restrict__ hfin,
    ushort* __restrict__ hpp,
    int* __restrict__ slots)
{
  const int bid = blockIdx.x;
  const int tid = threadIdx.x;
  const int wg = bid*4 + (tid >> 6);
  const int lane = tid & 63;
  const int lr = lane & 15, kg = lane >> 4;
  const int dir = wg >> 5, jt = wg & 31;
  const int j = jt*16 + lr;
  __shared__ ushort hsm[16][520];
  const ushort* Wp0 = Whb + ((long)(dir*G3E + j)        << 9) + kg*8;
  const ushort* Wp1 = Whb + ((long)(dir*G3E + 512 + j)  << 9) + kg*8;
  const ushort* Wp2 = Whb + ((long)(dir*G3E + 1024 + j) << 9) + kg*8;
  bf16x8 W0[16], W1[16], W2[16];
  #pragma unroll
  for (int i = 0; i < 16; ++i) {
    W0[i] = *(const bf16x8*)(Wp0 + i*32);
    W1[i] = *(const bf16x8*)(Wp1 + i*32);
    W2[i] = *(const bf16x8*)(Wp2 + i*32);
  }
  const float bh0 = bh[dir*G3E + j];
  const float bh1 = bh[dir*G3E + 512 + j];
  const float bh2 = bh[dir*G3E + 1024 + j];
  const float* GX = dir ? GXb : GXf;
  unsigned* hppu = (unsigned*)hpp;
  int* myslot = slots + dir*256 + (bid & 7)*32;
  int* dslots = slots + dir*256;
  float hreg[4] = {0.f, 0.f, 0.f, 0.f};
  float g0[4], g1[4], g2[4];
  {
    const int t0 = dir ? (TSN - 1) : 0;
    const float* gxp = GX + (long)t0*NB*G3E + j;
    #pragma unroll
    for (int r = 0; r < 4; ++r) {
      const float* g = gxp + (long)(kg*4 + r)*G3E;
      g0[r] = g[0]; g1[r] = g[512]; g2[r] = g[1024];
    }
  }
  for (int s = 0; s < TSN; ++s) {
    const int cur = s & 1;
    {
      const unsigned* hin = hppu + (cur*2 + dir)*4096;
      unsigned vdw[16];
      #pragma unroll
      for (int i = 0; i < 16; ++i) vdw[i] = agat_ld(hin + i*256 + tid);
      #pragma unroll
      for (int i = 0; i < 16; ++i) {
        int idx = i*256 + tid;
        int b = idx >> 8, jd = idx & 255;
        *(unsigned*)&hsm[b][jd*2] = vdw[i];
      }
    }
    __syncthreads();
    f32x4 a0 = {}, a1 = {}, a2 = {};
    #pragma unroll
    for (int i = 0; i < 16; ++i) {
      bf16x8 hf = *(const bf16x8*)&hsm[lr][kg*8 + i*32];
      a0 = __builtin_amdgcn_mfma_f32_16x16x32_bf16(hf, W0[i], a0, 0, 0, 0);
      a1 = __builtin_amdgcn_mfma_f32_16x16x32_bf16(hf, W1[i], a1, 0, 0, 0);
      a2 = __builtin_amdgcn_mfma_f32_16x16x32_bf16(hf, W2[i], a2, 0, 0, 0);
    }
    const int t = dir ? (TSN - 1 - s) : s;
    const int obase = ((cur^1)*2 + dir)*16*512;
    #pragma unroll
    for (int r = 0; r < 4; ++r) {
      int b = kg*4 + r;
      float rr = 1.f/(1.f + expf(-(g0[r] + a0[r] + bh0)));
      float zz = 1.f/(1.f + expf(-(g1[r] + a1[r] + bh1)));
      float nn = tanhf(g2[r] + rr*(a2[r] + bh2));
      float hn = (1.f - zz)*nn + zz*hreg[r];
      hreg[r] = hn;
      unsigned hv = f2bf(hn);
      unsigned pv = (unsigned)__shfl_xor((int)hv, 1);
      if ((lr & 1) == 0)
        agat_st(hppu + ((obase + b*512 + j) >> 1), hv | (pv << 16));
      long yi = bmajor ? ((long)b*TSN + t)*1024 + dir*512 + j
                       : ((long)t*NB + b)*1024 + dir*512 + j;
      Ybf[yi] = f2bf(hn);
      if (s == TSN - 1) hfin[b*1024 + dir*512 + j] = hn;
    }
    if (s + 1 < TSN) {
      const int tn = dir ? (TSN - 2 - s) : (s + 1);
      const float* gxp = GX + (long)tn*NB*G3E + j;
      #pragma unroll
      for (int r = 0; r < 4; ++r) {
        const float* g = gxp + (long)(kg*4 + r)*G3E;
        g0[r] = g[0]; g1[r] = g[512]; g2[r] = g[1024];
      }
      asm volatile("s_waitcnt vmcnt(0)" ::: "memory");
      __syncthreads();
      if (tid == 0)
        agat_st((unsigned*)myslot, (unsigned)(s + 1));
      if (tid < 8) {
        while ((int)agat_ld((const unsigned*)(dslots + tid*32)) < s + 1)
          __builtin_amdgcn_s_sleep(1);
      }
      __syncthreads();
    }
  }
}

// ---------------- row softmax f32 -> bf16 (pad to 448) ----------------
__global__ __launch_bounds__(256) void k_softmax_bf(
    const float* __restrict__ E, ushort* __restrict__ S)
{
  long row = blockIdx.x;
  const float* x = E + row*TSN;
  ushort* o = S + row*448;
  int tid = threadIdx.x;
  float v0 = (tid < TSN) ? x[tid] : -INFINITY;
  float v1 = (tid + 256 < TSN) ? x[tid + 256] : -INFINITY;
  __shared__ float red[256];
  red[tid] = fmaxf(v0, v1); __syncthreads();
  for (int oo = 128; oo; oo >>= 1) { if (tid < oo) red[tid] = fmaxf(red[tid], red[tid+oo]); __syncthreads(); }
  float m = red[0]; __syncthreads();
  float e0 = (tid < TSN) ? expf(v0 - m) : 0.f;
  float e1 = (tid + 256 < TSN) ? expf(v1 - m) : 0.f;
  red[tid] = e0 + e1; __syncthreads();
  for (int oo = 128; oo; oo >>= 1) { if (tid < oo) red[tid] += red[tid+oo]; __syncthreads(); }
  float inv = 1.f/red[0];
  if (tid < 192) o[tid + 256] = (tid + 256 < TSN) ? f2bf(e1*inv) : (ushort)0;
  o[tid] = f2bf(e0*inv);
}

// ---------------- fused selfcomb + answer attention -> encbf ----------------
__global__ __launch_bounds__(256) void k_ansatt2(
    const ushort* __restrict__ memsb, const float* __restrict__ ft,
    const float* __restrict__ gt, const ushort* __restrict__ outpb,
    const int* __restrict__ input_a, ushort* __restrict__ encb)
{
  int b = blockIdx.x >> 2;
  int d = (blockIdx.x & 3)*256 + threadIdx.x;
  __shared__ int ia[TSN];
  for (int i = threadIdx.x; i < TSN; i += 256) ia[i] = input_a[b*TSN + i];
  __syncthreads();
  float m = -INFINITY;
  #pragma unroll 4
  for (int t = 0; t < TSN; ++t) {
    float v = bf2f(memsb[((long)b*TSN + t)*1024 + d]);
    float e = ia[t] ? v*v : v;
    m = fmaxf(m, e);
  }
  float ssum = 0.f;
  #pragma unroll 4
  for (int t = 0; t < TSN; ++t) {
    float v = bf2f(memsb[((long)b*TSN + t)*1024 + d]);
    float e = ia[t] ? v*v : v;
    ssum += expf(e - m);
  }
  float inv = 1.f/ssum;
  #pragma unroll 4
  for (int t = 0; t < TSN; ++t) {
    long idx = ((long)b*TSN + t)*1024 + d;
    float v = bf2f(memsb[idx]);
    float e = ia[t] ? v*v : v;
    float gg = gt[idx];
    float selfo = gg*ft[idx] + (1.f - gg)*bf2f(outpb[idx]);
    encb[idx] = f2bf(selfo + expf(e - m)*inv*v);
  }
}

// ---------------- GRU phase for the persistent decoder ----------------
__device__ __forceinline__ void gru_phase(
    int bid, int tid,
    const ushort* __restrict__ A1, const ushort* __restrict__ W1,
    const ushort* __restrict__ A2, const ushort* __restrict__ W2,
    const float* __restrict__ gxadd, const float* __restrict__ bi,
    const float* __restrict__ bh,
    float* hreg, ushort* outb, ushort* catlow, float* psm)
{
  const int wv = tid >> 6, lane = tid & 63;
  const int lr = lane & 15, kg = lane >> 4;
  const int kc = wv*256;
  const int j = bid*16 + lr;
  f32x4 ax0 = {}, ax1 = {}, ax2 = {}, ah0 = {}, ah1 = {}, ah2 = {};
  const ushort* a1p = A1 + lr*1024 + kc + kg*8;
  const ushort* a2p = A2 + lr*1024 + kc + kg*8;
  const long wro = (long)j*1024 + kc + kg*8;
  const ushort* w10 = W1 + wro;
  const ushort* w11 = W1 + wro + 1024l*1024;
  const ushort* w12 = W1 + wro + 2048l*1024;
  const ushort* w20 = W2 + wro;
  const ushort* w21 = W2 + wro + 1024l*1024;
  const ushort* w22 = W2 + wro + 2048l*1024;
  #pragma unroll
  for (int k0 = 0; k0 < 256; k0 += 32) {
    bf16x8 a1v = ld8a(a1p + k0);
    bf16x8 a2v = ld8a(a2p + k0);
    ax0 = __builtin_amdgcn_mfma_f32_16x16x32_bf16(a1v, *(const bf16x8*)(w10 + k0), ax0, 0, 0, 0);
    ax1 = __builtin_amdgcn_mfma_f32_16x16x32_bf16(a1v, *(const bf16x8*)(w11 + k0), ax1, 0, 0, 0);
    ax2 = __builtin_amdgcn_mfma_f32_16x16x32_bf16(a1v, *(const bf16x8*)(w12 + k0), ax2, 0, 0, 0);
    ah0 = __builtin_amdgcn_mfma_f32_16x16x32_bf16(a2v, *(const bf16x8*)(w20 + k0), ah0, 0, 0, 0);
    ah1 = __builtin_amdgcn_mfma_f32_16x16x32_bf16(a2v, *(const bf16x8*)(w21 + k0), ah1, 0, 0, 0);
    ah2 = __builtin_amdgcn_mfma_f32_16x16x32_bf16(a2v, *(const bf16x8*)(w22 + k0), ah2, 0, 0, 0);
  }
  #pragma unroll
  for (int r = 0; r < 4; ++r) {
    int b = kg*4 + r;
    psm[((wv*6 + 0)*16 + b)*16 + lr] = ax0[r];
    psm[((wv*6 + 1)*16 + b)*16 + lr] = ax1[r];
    psm[((wv*6 + 2)*16 + b)*16 + lr] = ax2[r];
    psm[((wv*6 + 3)*16 + b)*16 + lr] = ah0[r];
    psm[((wv*6 + 4)*16 + b)*16 + lr] = ah1[r];
    psm[((wv*6 + 5)*16 + b)*16 + lr] = ah2[r];
  }
  __syncthreads();
  if (wv == 0) {
    #pragma unroll
    for (int r = 0; r < 4; ++r) {
      int b = kg*4 + r;
      float s0 = 0, s1 = 0, s2 = 0, s3 = 0, s4 = 0, s5 = 0;
      #pragma unroll
      for (int w2 = 0; w2 < 4; ++w2) {
        s0 += psm[((w2*6 + 0)*16 + b)*16 + lr];
        s1 += psm[((w2*6 + 1)*16 + b)*16 + lr];
        s2 += psm[((w2*6 + 2)*16 + b)*16 + lr];
        s3 += psm[((w2*6 + 3)*16 + b)*16 + lr];
        s4 += psm[((w2*6 + 4)*16 + b)*16 + lr];
        s5 += psm[((w2*6 + 5)*16 + b)*16 + lr];
      }
      float gx0 = s0, gx1 = s1, gx2 = s2;
      if (gxadd) {
        const float* g = gxadd + (long)b*G3D;
        gx0 += g[j]; gx1 += g[1024 + j]; gx2 += g[2048 + j];
      }
      if (bi) { gx0 += bi[j]; gx1 += bi[1024 + j]; gx2 += bi[2048 + j]; }
      float gh0 = s3 + bh[j], gh1 = s4 + bh[1024 + j], gh2 = s5 + bh[2048 + j];
      float rr = 1.f/(1.f + expf(-(gx0 + gh0)));
      float zz = 1.f/(1.f + expf(-(gx1 + gh1)));
      float nn = tanhf(gx2 + rr*gh2);
      float hn = (1.f - zz)*nn + zz*hreg[r];
      hreg[r] = hn;
      unsigned hv = f2bf(hn);
      unsigned pv = (unsigned)__shfl_xor((int)hv, 1);
      if ((lr & 1) == 0) {
        agat_st((unsigned*)outb + ((b*1024 + j) >> 1), hv | (pv << 16));
        if (catlow) agat_st((unsigned*)catlow + ((b*2048 + j) >> 1), hv | (pv << 16));
      }
    }
  }
}

// ---------------- persistent fused decoder: 64 blocks x 256, 4 grid bars/step ----------------
__global__ __launch_bounds__(256, 1) void k_dec_persist(
    const ushort* __restrict__ Wi0, const ushort* __restrict__ Wh0,
    const ushort* __restrict__ Wi1, const ushort* __restrict__ Wh1,
    const ushort* __restrict__ pW1b,
    const float* __restrict__ embGX, const float* __restrict__ dbh0,
    const float* __restrict__ dbi1, const float* __restrict__ dbh1,
    const float* __restrict__ pb1,
    const ushort* __restrict__ memdb,
    const float* __restrict__ hfin0, const float* __restrict__ hfin1,
    ushort* __restrict__ ctxb,
    ushort* __restrict__ h0b, ushort* __restrict__ h1b,
    ushort* __restrict__ catb,
    float* __restrict__ scb,
    ushort* __restrict__ hidAll,
    float* __restrict__ coveAll,
    float* __restrict__ covacc,
    int* __restrict__ slots)
{
  const int bid = blockIdx.x, tid = threadIdx.x;
  const int wv = tid >> 6, lane = tid & 63;
  const int lr = lane & 15, kg = lane >> 4;
  const int b4 = bid >> 2, q4 = bid & 3;
  __shared__ float psm[4*6*16*16];
  __shared__ float covsm[400];
  __shared__ float atl[400];
  __shared__ float red[256];
  __shared__ float psD[2][128][2];
  float hreg0[4] = {0,0,0,0}, hreg1[4] = {0,0,0,0};
  if (wv == 0) {
    #pragma unroll
    for (int r = 0; r < 4; ++r) {
      hreg0[r] = hfin0[(kg*4 + r)*1024 + bid*16 + lr];
      hreg1[r] = hfin1[(kg*4 + r)*1024 + bid*16 + lr];
    }
  }
  covsm[tid] = 0.f;
  if (tid < 144) covsm[256 + tid] = 0.f;
  __syncthreads();
  float closs_acc = 0.f;
  int ep = 0;
  for (int s = 0; s < NTT; ++s) {
    const int cur = s & 1;
    ushort* h0c = h0b + cur*16384;  ushort* h0n = h0b + (cur^1)*16384;
    ushort* h1c = h1b + cur*16384;  ushort* h1n = h1b + (cur^1)*16384;
    // ---- phase A: GRU layer 0 ----
    gru_phase(bid, tid, ctxb, Wi0, h0c, Wh0, embGX + (long)s*NB*G3D, nullptr, dbh0,
              hreg0, h0n, nullptr, psm);
    pbar(slots, 64, bid, tid, ++ep);
    // ---- phase B: GRU layer 1 ----
    gru_phase(bid, tid, h0n, Wi1, h1c, Wh1, nullptr, dbi1, dbh1,
              hreg1, h1n, catb, psm);
    pbar(slots, 64, bid, tid, ++ep);
    // ---- phase C: attention energies ----
    {
      const ushort* hrow = h1n + b4*1024 + lane*16;
      bf16x8 p0 = ld8a(hrow), p1 = ld8a(hrow + 8);
      float hr[16];
      #pragma unroll
      for (int e = 0; e < 8; ++e) { hr[e] = bf2f((ushort)p0[e]); hr[8+e] = bf2f((ushort)p1[e]); }
      for (int i = 0; i < 25; ++i) {
        int t = q4*100 + wv*25 + i;
        const ushort* row = memdb + ((long)(b4*TSN + t))*1024 + lane*16;
        bf16x8 r0 = *(const bf16x8*)row;
        bf16x8 r1 = *(const bf16x8*)(row + 8);
        float p = 0.f;
        #pragma unroll
        for (int e = 0; e < 8; ++e) p += hr[e]*bf2f((ushort)r0[e]) + hr[8+e]*bf2f((ushort)r1[e]);
        #pragma unroll
        for (int off = 32; off; off >>= 1) p += __shfl_xor(p, off);
        if (lane == 0) agat_st((unsigned*)&scb[b4*TSN + t], __float_as_uint(p));
      }
    }
    pbar(slots, 64, bid, tid, ++ep);
    // ---- phase D: coverage softmax + cov update + ctx ----
    {
      bool t1v = tid < 144;
      float sc0 = __uint_as_float(agat_ld((const unsigned*)&scb[b4*TSN + tid]));
      float sc1 = t1v ? __uint_as_float(agat_ld((const unsigned*)&scb[b4*TSN + 256 + tid])) : 0.f;
      float co0 = covsm[tid];
      float co1 = t1v ? covsm[256 + tid] : 0.f;
      float ce0 = sc0*(1.f - co0);
      float ce1 = t1v ? sc1*(1.f - co1) : -INFINITY;
      red[tid] = fmaxf(ce0, ce1); __syncthreads();
      for (int o = 128; o; o >>= 1) { if (tid < o) red[tid] = fmaxf(red[tid], red[tid+o]); __syncthreads(); }
      float m = red[0]; __syncthreads();
      float ex0 = expf(ce0 - m), ex1 = t1v ? expf(ce1 - m) : 0.f;
      red[tid] = ex0 + ex1; __syncthreads();
      for (int o = 128; o; o >>= 1) { if (tid < o) red[tid] += red[tid+o]; __syncthreads(); }
      float inv = 1.f/red[0]; __syncthreads();
      float a0 = ex0*inv, a1 = ex1*inv;
      atl[tid] = a0;
      if (t1v) atl[256 + tid] = a1;
      if (q4 == 0) {
        coveAll[((long)s*NB + b4)*TSN + tid] = ce0;
        if (t1v) coveAll[((long)s*NB + b4)*TSN + 256 + tid] = ce1;
      }
      red[tid] = fminf(a0, co0) + (t1v ? fminf(a1, co1) : 0.f);
      __syncthreads();
      for (int o = 128; o; o >>= 1) { if (tid < o) red[tid] += red[tid+o]; __syncthreads(); }
      if (tid == 0 && q4 == 0) closs_acc += red[0];
      __syncthreads();
      covsm[tid] = co0 + a0;
      if (t1v) covsm[256 + tid] = co1 + a1;
      __syncthreads();
      // ctx over this block's d-quarter
      int th = tid >> 7, dw = tid & 127;
      int d0 = q4*256 + dw*2;
      float s0 = 0.f, s1 = 0.f;
      const unsigned* cb = (const unsigned*)memdb + ((((long)(b4*TSN + th*200))*1024 + d0) >> 1);
      #pragma unroll 8
      for (int t = 0; t < 200; ++t) {
        unsigned dv = cb[(long)t*512];
        float a = atl[th*200 + t];
        s0 += a*bf2f((ushort)(dv & 0xffffu));
        s1 += a*bf2f((ushort)(dv >> 16));
      }
      psD[th][dw][0] = s0; psD[th][dw][1] = s1;
      __syncthreads();
      if (tid < 128) {
        float c0 = psD[0][tid][0] + psD[1][tid][0];
        float c1 = psD[0][tid][1] + psD[1][tid][1];
        unsigned pk = (unsigned)f2bf(c0) | ((unsigned)f2bf(c1) << 16);
        int d0c = q4*256 + tid*2;
        agat_st((unsigned*)ctxb + ((b4*1024 + d0c) >> 1), pk);
        agat_st((unsigned*)catb + ((b4*2048 + 1024 + d0c) >> 1), pk);
      }
    }
    pbar(slots, 64, bid, tid, ++ep);
    // ---- phase E: hid = tanh(cat @ pW1^T + pb1) ----
    {
      const int kc = wv*512;
      f32x4 acc = {};
      const ushort* ap = catb + lr*2048 + kc + kg*8;
      const ushort* wp = pW1b + ((long)(bid*16 + lr))*2048 + kc + kg*8;
      #pragma unroll
      for (int k0 = 0; k0 < 512; k0 += 32)
        acc = __builtin_amdgcn_mfma_f32_16x16x32_bf16(ld8a(ap + k0), *(const bf16x8*)(wp + k0), acc, 0, 0, 0);
      #pragma unroll
      for (int r = 0; r < 4; ++r)
        psm[((wv*6 + 0)*16 + kg*4 + r)*16 + lr] = acc[r];
      __syncthreads();
      if (wv == 0) {
        #pragma unroll
        for (int r = 0; r < 4; ++r) {
          int b = kg*4 + r;
          float sum = 0.f;
          #pragma unroll
          for (int w2 = 0; w2 < 4; ++w2) sum += psm[((w2*6 + 0)*16 + b)*16 + lr];
          hidAll[((long)s*NB + b)*1024 + bid*16 + lr] = f2bf(tanhf(sum + pb1[bid*16 + lr]));
        }
      }
      __syncthreads();   // protect psm reuse by next step's phase A
    }
    // no global barrier here (E->A hazard-free; next A-barrier orders B vs E)
  }
  if (tid == 0 && q4 == 0) atomicAdd(covacc, closs_acc);
}

// ---------------- batched logits ----------------
__global__ __launch_bounds__(256) void k_logits_all(
    const ushort* __restrict__ hidAll,
    const ushort* __restrict__ pW2b,
    const float* __restrict__ pb2,
    float* __restrict__ outp)
{
  const int wave = threadIdx.x >> 6, lane = threadIdx.x & 63;
  const int lr = lane & 15, kg = lane >> 4;
  const int n0 = blockIdx.x*256 + wave*64;
  const int m0 = blockIdx.y*128;
  f32x4 acc[8][4] = {};
  for (int k0 = 0; k0 < 1024; k0 += 32) {
    bf16x8 bfr[4];
    #pragma unroll
    for (int nt = 0; nt < 4; ++nt)
      bfr[nt] = *(const bf16x8*)&pW2b[(long)(n0 + nt*16 + lr)*1024 + k0 + kg*8];
    #pragma unroll
    for (int mt = 0; mt < 8; ++mt) {
      bf16x8 af = *(const bf16x8*)&hidAll[(long)(m0 + mt*16 + lr)*1024 + k0 + kg*8];
      #pragma unroll
      for (int nt = 0; nt < 4; ++nt)
        acc[mt][nt] = __builtin_amdgcn_mfma_f32_16x16x32_bf16(af, bfr[nt], acc[mt][nt], 0, 0, 0);
    }
  }
  #pragma unroll
  for (int nt = 0; nt < 4; ++nt) {
    int v = n0 + nt*16 + lr;
    if (v >= NEXT) continue;
    float pb = (v < NV) ? pb2[v] : 0.f;
    #pragma unroll
    for (int mt = 0; mt < 8; ++mt) {
      #pragma unroll
      for (int r = 0; r < 4; ++r) {
        int m = m0 + mt*16 + kg*4 + r;
        int s = m >> 4, b = m & 15;
        float e = (v < NV) ? (acc[mt][nt][r] + pb) : 0.f;
        if (e == 0.f) e = NEG_INF;
        outp[((long)b*NTT + s)*NEXT + v] = e;
      }
    }
  }
}

// ---------------- copy-scatter compose ----------------
__device__ __forceinline__ float dec_f(unsigned e) {
  return (e & 0x80000000u) ? __uint_as_float(e ^ 0x80000000u) : __uint_as_float(~e);
}
__global__ __launch_bounds__(512) void k_compose_all(
    const int* __restrict__ ids, const float* __restrict__ coveAll,
    unsigned* __restrict__ ubuf, float* __restrict__ outp)
{
  int b = blockIdx.x, tid = threadIdx.x;
  int v = 0;
  if (tid < TSN) v = ids[b*TSN + tid];
  unsigned* up = ubuf + (long)b*NEXT;
  for (int s = 0; s < NTT; ++s) {
    if (tid < TSN) {
      float ce = coveAll[((long)s*NB + b)*TSN + tid];
      unsigned bb = __float_as_uint(ce);
      unsigned enc = (bb & 0x80000000u) ? ~bb : (bb | 0x80000000u);
      atomicMax(&up[v], enc);
    }
    __syncthreads();
    if (tid < TSN) {
      unsigned u = __hip_atomic_load(&up[v], __ATOMIC_RELAXED, __HIP_MEMORY_SCOPE_AGENT);
      float o = dec_f(u);
      long oi = ((long)b*NTT + s)*NEXT + v;
      float e = outp[oi];
      if (e == NEG_INF) e = 0.f;
      float lg = e + o;
      if (lg == 0.f) lg = NEG_INF;
      outp[oi] = lg;
    }
    __syncthreads();
    if (tid < TSN)
      __hip_atomic_store(&up[v], 0u, __ATOMIC_RELAXED, __HIP_MEMORY_SCOPE_AGENT);
    __syncthreads();
  }
}

// ---------------- final coverage-loss scalar ----------------
__global__ void k_covout(const float* __restrict__ covacc, float* __restrict__ outp)
{
  outp[(long)NB*NTT*NEXT] = covacc[0] * (1.0f/(NB*NTT));
}

// ==================== host ====================
extern "C" void kernel_launch(void* const* d_in, const int* in_sizes, int n_in,
                              void* d_out, int out_size, void* d_ws, size_t ws_size,
                              hipStream_t stream) {
  (void)in_sizes; (void)n_in; (void)out_size; (void)ws_size;
  const float* enc_emb = (const float*)d_in[0];
  const float* ans_emb = (const float*)d_in[1];
  const float* dec_emb = (const float*)d_in[2];
  const float* eWi0 = (const float*)d_in[3];
  const float* eWh0 = (const float*)d_in[4];
  const float* ebi0 = (const float*)d_in[5];
  const float* ebh0 = (const float*)d_in[6];
  const float* eWi1 = (const float*)d_in[7];
  const float* eWh1 = (const float*)d_in[8];
  const float* ebi1 = (const float*)d_in[9];
  const float* ebh1 = (const float*)d_in[10];
  const float* trans_W = (const float*)d_in[11];
  const float* trans_b = (const float*)d_in[12];
  const float* upd_W = (const float*)d_in[13];
  const float* gate_W = (const float*)d_in[14];
  const float* dWi0 = (const float*)d_in[15];
  const float* dWh0 = (const float*)d_in[16];
  const float* dbi0 = (const float*)d_in[17];
  const float* dbh0 = (const float*)d_in[18];
  const float* dWi1 = (const float*)d_in[19];
  const float* dWh1 = (const float*)d_in[20];
  const float* dbi1 = (const float*)d_in[21];
  const float* dbh1 = (const float*)d_in[22];
  const float* dtrans_W = (const float*)d_in[23];
  const float* dtrans_b = (const float*)d_in[24];
  const float* pW1 = (const float*)d_in[25];
  const float* pb1 = (const float*)d_in[26];
  const float* pW2 = (const float*)d_in[27];
  const float* pb2 = (const float*)d_in[28];
  const int* input_s = (const int*)d_in[29];
  const int* ext_ids = (const int*)d_in[30];
  const int* input_q = (const int*)d_in[31];
  const int* input_a = (const int*)d_in[32];
  float* out = (float*)d_out;

  float* ws = (float*)d_ws;
  size_t off = 0;
  auto alloc = [&](size_t n) { float* p = ws + off; off += (n + 15) & ~(size_t)15; return p; };
  auto alloch = [&](size_t nh) { return (ushort*)alloc((nh + 1) / 2); };

  // --- small persistent ---
  ushort* hpp  = alloch(2ull*2*NB*HENC);
  int*   bar   = (int*)alloc(4096);   // scan L0 [0,512), scan L1 [512,1024), dec [1024,3072)
  float* covacc= alloc(4);
  float* cov   = alloc(NB*TSN);
  unsigned* ubuf = (unsigned*)alloc((size_t)NB*NEXT);
  float* hfin0 = alloc(NB*HD2);
  float* hfin1 = alloc(NB*HD2);
  float* scb   = alloc(NB*TSN);
  ushort* h0b  = alloch(2ull*NB*HD2);
  ushort* h1b  = alloch(2ull*NB*HD2);
  ushort* ctxbf= alloch(2ull*NB*HD2);
  ushort* catbf= alloch((size_t)NB*2048);
  ushort* hidAll = alloch((size_t)NTT*NB*HD2);
  float* coveAll = alloc((size_t)NTT*NB*TSN);

  // --- bf16 weights ---
  ushort* eWi0c   = alloch(2ull*G3E*384);
  ushort* eWi1c   = alloch(2ull*G3E*1024);
  ushort* Whb0    = alloch(2ull*G3E*HENC);
  ushort* Whb1    = alloch(2ull*G3E*HENC);
  ushort* transWb = alloch(1024ull*1024);
  ushort* updWb   = alloch(1024ull*2048);
  ushort* gateWb  = alloch(1024ull*2048);
  ushort* dtransWb= alloch(1024ull*1024);
  ushort* dWi0e   = alloch(3072ull*320);
  ushort* dWi0c   = alloch(3072ull*1024);
  ushort* dWh0b   = alloch(3072ull*1024);
  ushort* dWi1b   = alloch(3072ull*1024);
  ushort* dWh1b   = alloch(3072ull*1024);
  ushort* pW1b    = alloch(1024ull*2048);

  // --- alias region: [GX | X0c | Y0bf | ft] reused later as pW2b (+outpTb) ---
  size_t regionStart = off;
  float*  GX   = alloc(2ull*6400*G3E);
  ushort* X0c  = alloch(6400ull*384);
  ushort* Y0bf = alloch(6400ull*1024);
  float*  ft   = alloc(6400ull*HD2);
  ushort* pW2b   = (ushort*)(ws + regionStart);
  ushort* outpTb = (ushort*)(ws + regionStart + 26000000);

  // --- big buffers ---
  ushort* outpbf = alloch(6400ull*HD2);
  ushort* memsbf = alloch(6400ull*HD2);
  float*  scratchC = alloc(6400ull*HD2);
  float*  energ  = alloc((size_t)NB*TSN*TSN);
  ushort* scoresb= alloch((size_t)NB*TSN*448);
  ushort* ctx_bf = alloch(6400ull*HD2);
  ushort* memd_bf= alloch(6400ull*HD2);
  ushort* encbf  = alloch(6400ull*HD2);
  ushort* embqb  = alloch(512ull*320);
  float*  embGX  = alloc(512ull*G3D);

  // ---------------- one-time casts ----------------
  k_embed_bf<<<9600, 256, 0, stream>>>(enc_emb, ans_emb, input_s, input_a, X0c);
  k_castw<<<4608, 256, 0, stream>>>(eWi0, eWi0c, 3072, 3072ull*384, 332, 384, 332, 0);
  k_castw<<<12288, 256, 0, stream>>>(eWi1, eWi1c, 3072, 3072ull*1024, 1024, 1024, 1024, 0);
  k_castw<<<6144, 256, 0, stream>>>(eWh0, Whb0, 3072, 3072ull*512, 512, 512, 512, 0);
  k_castw<<<6144, 256, 0, stream>>>(eWh1, Whb1, 3072, 3072ull*512, 512, 512, 512, 0);
  k_castw<<<4096, 256, 0, stream>>>(trans_W, transWb, 1024, 1024ull*1024, 1024, 1024, 1024, 0);
  k_castw<<<8192, 256, 0, stream>>>(upd_W,  updWb,  1024, 1024ull*2048, 2048, 2048, 2048, 0);
  k_castw<<<8192, 256, 0, stream>>>(gate_W, gateWb, 1024, 1024ull*2048, 2048, 2048, 2048, 0);
  k_castw<<<4096, 256, 0, stream>>>(dtrans_W, dtransWb, 1024, 1024ull*1024, 1024, 1024, 1024, 0);
  k_castw<<<3840, 256, 0, stream>>>(dWi0, dWi0e, 3072, 3072ull*320, 300, 320, 1324, 0);
  k_castw<<<12288, 256, 0, stream>>>(dWi0, dWi0c, 3072, 3072ull*1024, 1024, 1024, 1324, 300);
  k_castw<<<12288, 256, 0, stream>>>(dWh0, dWh0b, 3072, 3072ull*1024, 1024, 1024, 1024, 0);
  k_castw<<<12288, 256, 0, stream>>>(dWi1, dWi1b, 3072, 3072ull*1024, 1024, 1024, 1024, 0);
  k_castw<<<12288, 256, 0, stream>>>(dWh1, dWh1b, 3072, 3072ull*1024, 1024, 1024, 1024, 0);
  k_castw<<<8192, 256, 0, stream>>>(pW1, pW1b, 1024, 1024ull*2048, 2048, 2048, 2048, 0);

  hipMemsetAsync(bar, 0, 16384, stream);

  // ---------------- encoder layer 0 ----------------
  k_mfma_nt<<<dim3(100,24,2), 256, 0, stream>>>(X0c, eWi0c, ebi0, GX, nullptr,
      6400, G3E, 384, 384, 384, G3E, 0, (long)G3E*384, 6400ull*G3E, G3E, 0, 0);
  hipMemsetAsync(hpp, 0, 2ull*2*NB*HENC*2, stream);
  k_scan_mfma<<<16, 256, 0, stream>>>(GX, GX + 6400ull*G3E, Whb0, ebh0,
      Y0bf, 0, hfin0, hpp, bar);
  // ---------------- encoder layer 1 ----------------
  k_mfma_nt<<<dim3(100,24,2), 256, 0, stream>>>(Y0bf, eWi1c, ebi1, GX, nullptr,
      6400, G3E, 1024, 1024, 1024, G3E, 0, (long)G3E*1024, 6400ull*G3E, G3E, 0, 0);
  hipMemsetAsync(hpp, 0, 2ull*2*NB*HENC*2, stream);
  k_scan_mfma<<<16, 256, 0, stream>>>(GX, GX + 6400ull*G3E, Whb1, ebh1,
      outpbf, 1, hfin1, hpp, bar + 512);

  // ---------------- self/answer attention ----------------
  k_mfma_nt<<<dim3(100,16,1), 256, 0, stream>>>(outpbf, transWb, trans_b, scratchC, memsbf,
      6400, HD2, 1024, 1024, 1024, HD2, 0, 0, 0, 0, 0, 0);
  k_mfma_nt<<<dim3(7,7,16), 256, 0, stream>>>(outpbf, memsbf, nullptr, energ, nullptr,
      TSN, TSN, 1024, 1024, 1024, TSN, (long)TSN*1024, (long)TSN*1024, (long)TSN*TSN, 0, 0, 0);
  k_softmax_bf<<<NB*TSN, 256, 0, stream>>>(energ, scoresb);
  k_transpose_hh<<<dim3(14,32,16), 256, 0, stream>>>(outpbf, outpTb);
  k_mfma_nt<<<dim3(7,16,16), 256, 0, stream>>>(scoresb, outpTb, nullptr, scratchC, ctx_bf,
      TSN, HD2, 448, 448, 448, HD2, (long)TSN*448, (long)HD2*448, (long)TSN*HD2, 0, 0, 0);
  k_mfma_nt<<<dim3(100,16,1), 256, 0, stream>>>(outpbf, updWb,        nullptr, ft, nullptr,
      6400, HD2, 1024, 1024, 2048, HD2, 0, 0, 0, 0, 0, 0);
  k_mfma_nt<<<dim3(100,16,1), 256, 0, stream>>>(ctx_bf, updWb + 1024, nullptr, ft, nullptr,
      6400, HD2, 1024, 1024, 2048, HD2, 0, 0, 0, 0, 1, 1);
  k_mfma_nt<<<dim3(100,16,1), 256, 0, stream>>>(outpbf, gateWb,       nullptr, scratchC, nullptr,
      6400, HD2, 1024, 1024, 2048, HD2, 0, 0, 0, 0, 0, 0);
  k_mfma_nt<<<dim3(100,16,1), 256, 0, stream>>>(ctx_bf, gateWb + 1024, nullptr, scratchC, nullptr,
      6400, HD2, 1024, 1024, 2048, HD2, 0, 0, 0, 0, 1, 2);
  k_ansatt2<<<64, 256, 0, stream>>>(memsbf, ft, scratchC, outpbf, input_a, encbf);
  // region now dead: cast pW2
  k_castw<<<200704, 256, 0, stream>>>(pW2, pW2b, NV, (long)NVP*1024, 1024, 1024, 1024, 0);
  k_mfma_nt<<<dim3(100,16,1), 256, 0, stream>>>(encbf, dtransWb, dtrans_b, scratchC, memd_bf,
      6400, HD2, 1024, 1024, 1024, HD2, 0, 0, 0, 0, 0, 0);

  // ---------------- decoder precompute ----------------
  k_embq_bf<<<640, 256, 0, stream>>>(dec_emb, input_q, embqb);
  k_mfma_nt<<<dim3(8,48,1), 256, 0, stream>>>(embqb, dWi0e, dbi0, embGX, nullptr,
      NTT*NB, G3D, 320, 320, 320, G3D, 0, 0, 0, 0, 0, 0);

  hipMemsetAsync(covacc, 0, 4, stream);
  hipMemsetAsync(ubuf, 0, (size_t)NB*NEXT*4, stream);
  hipMemsetAsync(ctxbf, 0, (size_t)NB*HD2*2, stream);
  k_cast<<<64, 256, 0, stream>>>(hfin0, h0b, 16384);
  k_cast<<<64, 256, 0, stream>>>(hfin1, h1b, 16384);

  // ---------------- persistent fused decoder ----------------
  k_dec_persist<<<64, 256, 0, stream>>>(
      dWi0c, dWh0b, dWi1b, dWh1b, pW1b,
      embGX, dbh0, dbi1, dbh1, pb1,
      memd_bf, hfin0, hfin1,
      ctxbf, h0b, h1b, catbf, scb,
      hidAll, coveAll, covacc, bar + 1024);

  // ---------------- batched logits + compose ----------------
  k_logits_all<<<dim3(196, 4), 256, 0, stream>>>(hidAll, pW2b, pb2, out);
  k_compose_all<<<NB, 512, 0, stream>>>(ext_ids, coveAll, ubuf, out);
  k_covout<<<1, 1, 0, stream>>>(covacc, out);
  (void)cov;
}

// Round 8
// 6910.287 us; speedup vs baseline: 1.1525x; 1.1525x over previous
//
#include <hip/hip_runtime.h>
#include <stdint.h>

#define TSN 400
#define NB 16
#define HENC 512
#define HD2 1024
#define G3E 1536
#define G3D 3072
#define EMBD 300
#define AEMB 32
#define NV 50000
#define NEXT 50100
#define NVP 50176
#define NTT 32
#define NEG_INF (-1.0e12f)

typedef __attribute__((ext_vector_type(8))) short bf16x8;
typedef __attribute__((ext_vector_type(4))) float f32x4;

__device__ __forceinline__ ushort f2bf(float f) {
  unsigned u = __float_as_uint(f);
  unsigned r = (u + 0x7fffu + ((u >> 16) & 1u)) >> 16;
  return (ushort)r;
}
__device__ __forceinline__ float bf2f(ushort h) {
  return __uint_as_float((unsigned)h << 16);
}
__device__ __forceinline__ unsigned agat_ld(const unsigned* p) {
  return __hip_atomic_load(p, __ATOMIC_RELAXED, __HIP_MEMORY_SCOPE_AGENT);
}
__device__ __forceinline__ void agat_st(unsigned* p, unsigned v) {
  __hip_atomic_store(p, v, __ATOMIC_RELAXED, __HIP_MEMORY_SCOPE_AGENT);
}

// ---------------- embeddings -> bf16, padded K=384 ----------------
__global__ __launch_bounds__(256) void k_embed_bf(
    const float* __restrict__ enc_emb, const float* __restrict__ ans_emb,
    const int* __restrict__ input_s, const int* __restrict__ input_a,
    ushort* __restrict__ X0)
{
  long i = (long)blockIdx.x*256 + threadIdx.x;
  if (i >= (long)TSN*NB*384) return;
  int c = (int)(i % 384);
  long r = i / 384;
  int b = (int)(r % NB);
  int t = (int)(r / NB);
  float v = 0.f;
  if (c < EMBD) v = enc_emb[(long)input_s[b*TSN + t]*EMBD + c];
  else if (c < 332) v = ans_emb[(long)input_a[b*TSN + t]*AEMB + (c - EMBD)];
  X0[i] = f2bf(v);
}

// ---------------- decoder emb -> bf16, padded K=320 ----------------
__global__ __launch_bounds__(256) void k_embq_bf(
    const float* __restrict__ dec_emb, const int* __restrict__ input_q,
    ushort* __restrict__ EQ)
{
  long i = (long)blockIdx.x*256 + threadIdx.x;
  if (i >= (long)NTT*NB*320) return;
  int c = (int)(i % 320);
  long r = i / 320;
  int b = (int)(r % NB);
  int s = (int)(r / NB);
  EQ[i] = (c < EMBD) ? f2bf(dec_emb[(long)input_q[b*33 + s]*EMBD + c]) : (ushort)0;
}

// ---------------- weight cast with pad ----------------
__global__ __launch_bounds__(256) void k_castw(
    const float* __restrict__ src, ushort* __restrict__ dst,
    int Nsrc, long total, int Ksrc, int Kdst, int ldsrc, int coloff)
{
  long i = (long)blockIdx.x*256 + threadIdx.x;
  if (i >= total) return;
  int k = (int)(i % Kdst);
  long n = i / Kdst;
  float v = (n < Nsrc && k < Ksrc) ? src[n*ldsrc + coloff + k] : 0.f;
  dst[i] = f2bf(v);
}

// ---------------- plain cast fp32 -> bf16 ----------------
__global__ __launch_bounds__(256) void k_cast(
    const float* __restrict__ s, ushort* __restrict__ d, long n)
{
  long i = (long)blockIdx.x*256 + threadIdx.x;
  if (i >= n) return;
  d[i] = f2bf(s[i]);
}

// ---------------- bf16 batched transpose with K-pad: out[b][c][r(448)] ----------------
__global__ __launch_bounds__(256) void k_transpose_hh(
    const ushort* __restrict__ in, ushort* __restrict__ out)
{
  __shared__ ushort tb[32][33];
  int b = blockIdx.z;
  int r0 = blockIdx.x*32, c0 = blockIdx.y*32;
  int tx = threadIdx.x & 31, ty = threadIdx.x >> 5;
  #pragma unroll
  for (int i = 0; i < 32; i += 8) {
    int r = r0 + ty + i, c = c0 + tx;
    tb[ty+i][tx] = (r < TSN) ? in[((long)b*TSN + r)*1024 + c] : (ushort)0;
  }
  __syncthreads();
  #pragma unroll
  for (int i = 0; i < 32; i += 8) {
    int c = c0 + ty + i, r = r0 + tx;
    out[((long)b*1024 + c)*448 + r] = tb[tx][ty+i];
  }
}

// ---------------- MFMA GEMM ----------------
__global__ __launch_bounds__(256) void k_mfma_nt(
    const ushort* __restrict__ Ab, const ushort* __restrict__ Wb,
    const float* __restrict__ bias, float* __restrict__ Cb, ushort* __restrict__ C2b,
    int M, int N, int K, int lda, int ldw, int ldc,
    long sA, long sW, long sC, long sBias, int accum, int act)
{
  __shared__ ushort As[64][72];
  __shared__ ushort Ws[64][72];
  const ushort* A = Ab + (long)blockIdx.z * sA;
  const ushort* W = Wb + (long)blockIdx.z * sW;
  float* C = Cb + (long)blockIdx.z * sC;
  const float* bi = bias ? bias + (long)blockIdx.z * sBias : nullptr;
  const int m0 = blockIdx.x*64, n0 = blockIdx.y*64;
  const int tid = threadIdx.x;
  const int wave = tid >> 6, lane = tid & 63;
  const int wm = wave >> 1, wn = wave & 1;
  const int lr = lane & 15, kg = lane >> 4;
  f32x4 acc[2][2] = {};
  for (int k0 = 0; k0 < K; k0 += 64) {
    __syncthreads();
    #pragma unroll
    for (int it = 0; it < 2; ++it) {
      int sidx = tid + it*256;
      int r = sidx >> 3, c = (sidx & 7)*8;
      bf16x8 av = {};
      bf16x8 wv = {};
      if (m0 + r < M) av = *(const bf16x8*)&A[(long)(m0+r)*lda + k0 + c];
      if (n0 + r < N) wv = *(const bf16x8*)&W[(long)(n0+r)*ldw + k0 + c];
      *(bf16x8*)&As[r][c] = av;
      *(bf16x8*)&Ws[r][c] = wv;
    }
    __syncthreads();
    #pragma unroll
    for (int kk = 0; kk < 2; ++kk) {
      bf16x8 af[2], bf[2];
      #pragma unroll
      for (int mt = 0; mt < 2; ++mt)
        af[mt] = *(const bf16x8*)&As[wm*32 + mt*16 + lr][kk*32 + kg*8];
      #pragma unroll
      for (int nt = 0; nt < 2; ++nt)
        bf[nt] = *(const bf16x8*)&Ws[wn*32 + nt*16 + lr][kk*32 + kg*8];
      #pragma unroll
      for (int mt = 0; mt < 2; ++mt)
        #pragma unroll
        for (int nt = 0; nt < 2; ++nt)
          acc[mt][nt] = __builtin_amdgcn_mfma_f32_16x16x32_bf16(af[mt], bf[nt], acc[mt][nt], 0, 0, 0);
    }
  }
  #pragma unroll
  for (int mt = 0; mt < 2; ++mt) {
    #pragma unroll
    for (int r = 0; r < 4; ++r) {
      int m = m0 + wm*32 + mt*16 + kg*4 + r;
      if (m >= M) continue;
      #pragma unroll
      for (int nt = 0; nt < 2; ++nt) {
        int n = n0 + wn*32 + nt*16 + lr;
        if (n >= N) continue;
        float v = acc[mt][nt][r];
        if (accum) v += C[(long)m*ldc + n];
        if (bi)    v += bi[n];
        if (act == 1) v = tanhf(v);
        else if (act == 2) v = 1.f/(1.f + expf(-v));
        C[(long)m*ldc + n] = v;
        if (C2b) C2b[(long)blockIdx.z*sC + (long)m*ldc + n] = f2bf(v);
      }
    }
  }
}

// ---------------- persistent MFMA bidirectional GRU scan v5 ----------------
// 16 blocks x 512 (8/dir). Wave = (j-tile, K-half): weights 96 VGPR/wave
// (register-resident), LDS partial reduce between K-half waves. Fence-free
// h exchange (write-through agent atomics) + per-dir 8-slot relaxed barrier.
__global__ __launch_bounds__(512, 1) void k_scan_mfma(
    const float* __restrict__ GXf, const float* __restrict__ GXb,
    const ushort* __restrict__ Whb,   // [2][1536][512] bf16
    const float* __restrict__ bh,     // [2][1536]
    ushort* __restrict__ Ybf, int bmajor,
    float* __restrict__ hfin,
    ushort* __restrict__ hpp,         // [2 ping][2 dir][16 b][512 j] bf16
    int* __restrict__ slots)          // [2 dir][8][32] ints
{
  const int bid = blockIdx.x;
  const int tid = threadIdx.x;
  const int w = tid >> 6;            // 0..7
  const int lane = tid & 63;
  const int lr = lane & 15, kg = lane >> 4;
  const int dir = bid >> 3;
  const int jt = (bid & 7)*4 + (w & 3);
  const int kh = w >> 2;
  const int j = jt*16 + lr;
  __shared__ ushort hsm[16][520];
  __shared__ float psum[4][3][16][16];
  const int kbase = kh*256;
  const ushort* Wp0 = Whb + ((long)(dir*G3E + j)        << 9) + kbase + kg*8;
  const ushort* Wp1 = Whb + ((long)(dir*G3E + 512 + j)  << 9) + kbase + kg*8;
  const ushort* Wp2 = Whb + ((long)(dir*G3E + 1024 + j) << 9) + kbase + kg*8;
  bf16x8 W0[8], W1[8], W2[8];
  #pragma unroll
  for (int i = 0; i < 8; ++i) {
    W0[i] = *(const bf16x8*)(Wp0 + i*32);
    W1[i] = *(const bf16x8*)(Wp1 + i*32);
    W2[i] = *(const bf16x8*)(Wp2 + i*32);
  }
  const float bh0 = bh[dir*G3E + j];
  const float bh1 = bh[dir*G3E + 512 + j];
  const float bh2 = bh[dir*G3E + 1024 + j];
  const float* GX = dir ? GXb : GXf;
  unsigned* hppu = (unsigned*)hpp;
  int* myslot = slots + dir*256 + (bid & 7)*32;
  int* dslots = slots + dir*256;
  float hreg[4] = {0.f, 0.f, 0.f, 0.f};
  float g0[4], g1[4], g2[4];
  if (kh == 0) {
    const int t0 = dir ? (TSN - 1) : 0;
    const float* gxp = GX + (long)t0*NB*G3E + j;
    #pragma unroll
    for (int r = 0; r < 4; ++r) {
      const float* g = gxp + (long)(kg*4 + r)*G3E;
      g0[r] = g[0]; g1[r] = g[512]; g2[r] = g[1024];
    }
  }
  for (int s = 0; s < TSN; ++s) {
    const int cur = s & 1;
    // ---- coalesced agent-atomic load of full h(dir) -> LDS ----
    {
      const unsigned* hin = hppu + (cur*2 + dir)*4096;
      unsigned vdw[8];
      #pragma unroll
      for (int i = 0; i < 8; ++i) vdw[i] = agat_ld(hin + i*512 + tid);
      #pragma unroll
      for (int i = 0; i < 8; ++i) {
        int idx = i*512 + tid;
        int b = idx >> 8, jd = idx & 255;
        *(unsigned*)&hsm[b][jd*2] = vdw[i];
      }
    }
    __syncthreads();
    f32x4 a0 = {}, a1 = {}, a2 = {};
    #pragma unroll
    for (int i = 0; i < 8; ++i) {
      bf16x8 hf = *(const bf16x8*)&hsm[lr][kbase + kg*8 + i*32];
      a0 = __builtin_amdgcn_mfma_f32_16x16x32_bf16(hf, W0[i], a0, 0, 0, 0);
      a1 = __builtin_amdgcn_mfma_f32_16x16x32_bf16(hf, W1[i], a1, 0, 0, 0);
      a2 = __builtin_amdgcn_mfma_f32_16x16x32_bf16(hf, W2[i], a2, 0, 0, 0);
    }
    if (kh == 1) {
      #pragma unroll
      for (int r = 0; r < 4; ++r) {
        int b = kg*4 + r;
        psum[w & 3][0][b][lr] = a0[r];
        psum[w & 3][1][b][lr] = a1[r];
        psum[w & 3][2][b][lr] = a2[r];
      }
    }
    __syncthreads();
    const int t = dir ? (TSN - 1 - s) : s;
    if (kh == 0) {
      const int obase = ((cur^1)*2 + dir)*16*512;
      #pragma unroll
      for (int r = 0; r < 4; ++r) {
        int b = kg*4 + r;
        float f0 = a0[r] + psum[w & 3][0][b][lr];
        float f1 = a1[r] + psum[w & 3][1][b][lr];
        float f2 = a2[r] + psum[w & 3][2][b][lr];
        float rr = 1.f/(1.f + expf(-(g0[r] + f0 + bh0)));
        float zz = 1.f/(1.f + expf(-(g1[r] + f1 + bh1)));
        float nn = tanhf(g2[r] + rr*(f2 + bh2));
        float hn = (1.f - zz)*nn + zz*hreg[r];
        hreg[r] = hn;
        unsigned hv = f2bf(hn);
        unsigned pv = (unsigned)__shfl_xor((int)hv, 1);
        if ((lr & 1) == 0)
          agat_st(hppu + ((obase + b*512 + j) >> 1), hv | (pv << 16));
        long yi = bmajor ? ((long)b*TSN + t)*1024 + dir*512 + j
                         : ((long)t*NB + b)*1024 + dir*512 + j;
        Ybf[yi] = f2bf(hn);
        if (s == TSN - 1) hfin[b*1024 + dir*512 + j] = hn;
      }
    }
    if (s + 1 < TSN) {
      if (kh == 0) {
        const int tn = dir ? (TSN - 2 - s) : (s + 1);
        const float* gxp = GX + (long)tn*NB*G3E + j;
        #pragma unroll
        for (int r = 0; r < 4; ++r) {
          const float* g = gxp + (long)(kg*4 + r)*G3E;
          g0[r] = g[0]; g1[r] = g[512]; g2[r] = g[1024];
        }
      }
      asm volatile("s_waitcnt vmcnt(0)" ::: "memory");
      __syncthreads();
      if (tid == 0)
        agat_st((unsigned*)myslot, (unsigned)(s + 1));
      if (tid < 8) {
        while ((int)agat_ld((const unsigned*)(dslots + tid*32)) < s + 1)
          __builtin_amdgcn_s_sleep(1);
      }
      __syncthreads();
    }
  }
}

// ---------------- row softmax f32 -> bf16 (pad to 448) ----------------
__global__ __launch_bounds__(256) void k_softmax_bf(
    const float* __restrict__ E, ushort* __restrict__ S)
{
  long row = blockIdx.x;
  const float* x = E + row*TSN;
  ushort* o = S + row*448;
  int tid = threadIdx.x;
  float v0 = (tid < TSN) ? x[tid] : -INFINITY;
  float v1 = (tid + 256 < TSN) ? x[tid + 256] : -INFINITY;
  __shared__ float red[256];
  red[tid] = fmaxf(v0, v1); __syncthreads();
  for (int oo = 128; oo; oo >>= 1) { if (tid < oo) red[tid] = fmaxf(red[tid], red[tid+oo]); __syncthreads(); }
  float m = red[0]; __syncthreads();
  float e0 = (tid < TSN) ? expf(v0 - m) : 0.f;
  float e1 = (tid + 256 < TSN) ? expf(v1 - m) : 0.f;
  red[tid] = e0 + e1; __syncthreads();
  for (int oo = 128; oo; oo >>= 1) { if (tid < oo) red[tid] += red[tid+oo]; __syncthreads(); }
  float inv = 1.f/red[0];
  if (tid < 192) o[tid + 256] = (tid + 256 < TSN) ? f2bf(e1*inv) : (ushort)0;
  o[tid] = f2bf(e0*inv);
}

// ---------------- fused selfcomb + answer attention -> encbf ----------------
__global__ __launch_bounds__(256) void k_ansatt2(
    const ushort* __restrict__ memsb, const float* __restrict__ ft,
    const float* __restrict__ gt, const ushort* __restrict__ outpb,
    const int* __restrict__ input_a, ushort* __restrict__ encb)
{
  int b = blockIdx.x >> 2;
  int d = (blockIdx.x & 3)*256 + threadIdx.x;
  __shared__ int ia[TSN];
  for (int i = threadIdx.x; i < TSN; i += 256) ia[i] = input_a[b*TSN + i];
  __syncthreads();
  float m = -INFINITY;
  #pragma unroll 4
  for (int t = 0; t < TSN; ++t) {
    float v = bf2f(memsb[((long)b*TSN + t)*1024 + d]);
    float e = ia[t] ? v*v : v;
    m = fmaxf(m, e);
  }
  float ssum = 0.f;
  #pragma unroll 4
  for (int t = 0; t < TSN; ++t) {
    float v = bf2f(memsb[((long)b*TSN + t)*1024 + d]);
    float e = ia[t] ? v*v : v;
    ssum += expf(e - m);
  }
  float inv = 1.f/ssum;
  #pragma unroll 4
  for (int t = 0; t < TSN; ++t) {
    long idx = ((long)b*TSN + t)*1024 + d;
    float v = bf2f(memsb[idx]);
    float e = ia[t] ? v*v : v;
    float gg = gt[idx];
    float selfo = gg*ft[idx] + (1.f - gg)*bf2f(outpb[idx]);
    encb[idx] = f2bf(selfo + expf(e - m)*inv*v);
  }
}

// ---------------- decoder GRU layer: 64 blocks x 64 (1 wave each) ----------------
__global__ __launch_bounds__(64) void k_gru_dec(
    const ushort* __restrict__ A1, const ushort* __restrict__ W1,
    const ushort* __restrict__ A2, const ushort* __restrict__ W2,
    const float* __restrict__ gxadd, const float* __restrict__ bi,
    const float* __restrict__ bh,
    const float* __restrict__ hprev, float* __restrict__ hout,
    ushort* __restrict__ houtb, ushort* __restrict__ catb)
{
  const int wg = blockIdx.x;
  const int lane = threadIdx.x;
  const int lr = lane & 15, kg = lane >> 4;
  const int j = wg*16 + lr;
  const ushort* w1p0 = W1 + ((long)(j)        << 10) + kg*8;
  const ushort* w1p1 = W1 + ((long)(1024 + j) << 10) + kg*8;
  const ushort* w1p2 = W1 + ((long)(2048 + j) << 10) + kg*8;
  const ushort* w2p0 = W2 + ((long)(j)        << 10) + kg*8;
  const ushort* w2p1 = W2 + ((long)(1024 + j) << 10) + kg*8;
  const ushort* w2p2 = W2 + ((long)(2048 + j) << 10) + kg*8;
  const ushort* a1p = A1 + lr*1024 + kg*8;
  const ushort* a2p = A2 + lr*1024 + kg*8;
  f32x4 x0 = {}, x1 = {}, x2 = {}, h0 = {}, h1 = {}, h2 = {};
  #pragma unroll 4
  for (int k0 = 0; k0 < 1024; k0 += 32) {
    bf16x8 a1v = *(const bf16x8*)(a1p + k0);
    bf16x8 a2v = *(const bf16x8*)(a2p + k0);
    x0 = __builtin_amdgcn_mfma_f32_16x16x32_bf16(a1v, *(const bf16x8*)(w1p0 + k0), x0, 0, 0, 0);
    x1 = __builtin_amdgcn_mfma_f32_16x16x32_bf16(a1v, *(const bf16x8*)(w1p1 + k0), x1, 0, 0, 0);
    x2 = __builtin_amdgcn_mfma_f32_16x16x32_bf16(a1v, *(const bf16x8*)(w1p2 + k0), x2, 0, 0, 0);
    h0 = __builtin_amdgcn_mfma_f32_16x16x32_bf16(a2v, *(const bf16x8*)(w2p0 + k0), h0, 0, 0, 0);
    h1 = __builtin_amdgcn_mfma_f32_16x16x32_bf16(a2v, *(const bf16x8*)(w2p1 + k0), h1, 0, 0, 0);
    h2 = __builtin_amdgcn_mfma_f32_16x16x32_bf16(a2v, *(const bf16x8*)(w2p2 + k0), h2, 0, 0, 0);
  }
  float bi0 = bi ? bi[j] : 0.f, bi1 = bi ? bi[1024 + j] : 0.f, bi2 = bi ? bi[2048 + j] : 0.f;
  float bh0 = bh[j], bh1 = bh[1024 + j], bh2 = bh[2048 + j];
  #pragma unroll
  for (int r = 0; r < 4; ++r) {
    int b = kg*4 + r;
    float gxa0 = gxadd ? gxadd[(long)b*G3D + j]        : 0.f;
    float gxa1 = gxadd ? gxadd[(long)b*G3D + 1024 + j] : 0.f;
    float gxa2 = gxadd ? gxadd[(long)b*G3D + 2048 + j] : 0.f;
    float gx0 = x0[r] + gxa0 + bi0;
    float gx1 = x1[r] + gxa1 + bi1;
    float gx2 = x2[r] + gxa2 + bi2;
    float gh0 = h0[r] + bh0, gh1 = h1[r] + bh1, gh2 = h2[r] + bh2;
    float rr = 1.f/(1.f + expf(-(gx0 + gh0)));
    float zz = 1.f/(1.f + expf(-(gx1 + gh1)));
    float nn = tanhf(gx2 + rr*gh2);
    float hp = hprev[b*1024 + j];
    float hn = (1.f - zz)*nn + zz*hp;
    hout[b*1024 + j] = hn;
    houtb[b*1024 + j] = f2bf(hn);
    if (catb) catb[(long)b*2048 + j] = f2bf(hn);
  }
}

// ---------------- fused decoder attention ----------------
__global__ __launch_bounds__(1024) void k_dec_attn2(
    const ushort* __restrict__ h1b, const ushort* __restrict__ memdb,
    float* __restrict__ cov, float* __restrict__ covOut, float* __restrict__ covacc,
    ushort* __restrict__ ctxn, ushort* __restrict__ catb)
{
  const int b = blockIdx.x, tid = threadIdx.x;
  const int wv = tid >> 6, ln = tid & 63;
  __shared__ float sc[TSN];
  __shared__ float at[TSN];
  __shared__ float red[1024];
  float hreg[16];
  {
    bf16x8 hv0 = *(const bf16x8*)&h1b[b*1024 + ln*16];
    bf16x8 hv1 = *(const bf16x8*)&h1b[b*1024 + ln*16 + 8];
    #pragma unroll
    for (int e = 0; e < 8; ++e) { hreg[e] = bf2f((ushort)hv0[e]); hreg[8+e] = bf2f((ushort)hv1[e]); }
  }
  for (int t = wv; t < TSN; t += 16) {
    const ushort* row = memdb + ((long)b*TSN + t)*1024 + ln*16;
    bf16x8 r0 = *(const bf16x8*)row;
    bf16x8 r1 = *(const bf16x8*)(row + 8);
    float p = 0.f;
    #pragma unroll
    for (int e = 0; e < 8; ++e) p += hreg[e]*bf2f((ushort)r0[e]) + hreg[8+e]*bf2f((ushort)r1[e]);
    #pragma unroll
    for (int off = 32; off; off >>= 1) p += __shfl_xor(p, off);
    if (ln == 0) sc[t] = p;
  }
  __syncthreads();
  float ce = -INFINITY, co = 0.f;
  if (tid < TSN) { co = cov[b*TSN + tid]; ce = sc[tid]*(1.f - co); }
  red[tid] = ce; __syncthreads();
  for (int o = 512; o; o >>= 1) { if (tid < o) red[tid] = fmaxf(red[tid], red[tid+o]); __syncthreads(); }
  float m = red[0]; __syncthreads();
  float ex = (tid < TSN) ? expf(ce - m) : 0.f;
  red[tid] = ex; __syncthreads();
  for (int o = 512; o; o >>= 1) { if (tid < o) red[tid] += red[tid+o]; __syncthreads(); }
  float inv = 1.f/red[0]; __syncthreads();
  float closs = 0.f;
  if (tid < TSN) {
    float a = ex*inv;
    at[tid] = a;
    cov[b*TSN + tid] = co + a;
    covOut[b*TSN + tid] = ce;
    closs = fminf(a, co);
  }
  red[tid] = closs; __syncthreads();
  for (int o = 512; o; o >>= 1) { if (tid < o) red[tid] += red[tid+o]; __syncthreads(); }
  if (tid == 0) atomicAdd(covacc, red[0]);
  __syncthreads();
  float s = 0.f;
  const ushort* col = memdb + (long)b*TSN*1024 + tid;
  #pragma unroll 8
  for (int t = 0; t < TSN; ++t) s += at[t]*bf2f(col[(long)t*1024]);
  ushort hv = f2bf(s);
  ctxn[b*1024 + tid] = hv;
  catb[(long)b*2048 + 1024 + tid] = hv;
}

// ---------------- hid = tanh(cat @ pW1^T + pb1): 64 blocks x 64 ----------------
__global__ __launch_bounds__(64) void k_hid(
    const ushort* __restrict__ catb, const ushort* __restrict__ W,
    const float* __restrict__ pb1, ushort* __restrict__ hidb)
{
  const int wg = blockIdx.x;
  const int lane = threadIdx.x;
  const int lr = lane & 15, kg = lane >> 4;
  const int n = wg*16 + lr;
  f32x4 acc = {};
  const ushort* ap = catb + lr*2048 + kg*8;
  const ushort* wp = W + ((long)n << 11) + kg*8;
  #pragma unroll 8
  for (int k0 = 0; k0 < 2048; k0 += 32)
    acc = __builtin_amdgcn_mfma_f32_16x16x32_bf16(*(const bf16x8*)(ap + k0), *(const bf16x8*)(wp + k0), acc, 0, 0, 0);
  float bv = pb1[n];
  #pragma unroll
  for (int r = 0; r < 4; ++r) {
    int b = kg*4 + r;
    hidb[b*1024 + n] = f2bf(tanhf(acc[r] + bv));
  }
}

// ---------------- batched logits ----------------
__global__ __launch_bounds__(256) void k_logits_all(
    const ushort* __restrict__ hidAll,
    const ushort* __restrict__ pW2b,
    const float* __restrict__ pb2,
    float* __restrict__ outp)
{
  const int wave = threadIdx.x >> 6, lane = threadIdx.x & 63;
  const int lr = lane & 15, kg = lane >> 4;
  const int n0 = blockIdx.x*256 + wave*64;
  const int m0 = blockIdx.y*128;
  f32x4 acc[8][4] = {};
  for (int k0 = 0; k0 < 1024; k0 += 32) {
    bf16x8 bfr[4];
    #pragma unroll
    for (int nt = 0; nt < 4; ++nt)
      bfr[nt] = *(const bf16x8*)&pW2b[(long)(n0 + nt*16 + lr)*1024 + k0 + kg*8];
    #pragma unroll
    for (int mt = 0; mt < 8; ++mt) {
      bf16x8 af = *(const bf16x8*)&hidAll[(long)(m0 + mt*16 + lr)*1024 + k0 + kg*8];
      #pragma unroll
      for (int nt = 0; nt < 4; ++nt)
        acc[mt][nt] = __builtin_amdgcn_mfma_f32_16x16x32_bf16(af, bfr[nt], acc[mt][nt], 0, 0, 0);
    }
  }
  #pragma unroll
  for (int nt = 0; nt < 4; ++nt) {
    int v = n0 + nt*16 + lr;
    if (v >= NEXT) continue;
    float pb = (v < NV) ? pb2[v] : 0.f;
    #pragma unroll
    for (int mt = 0; mt < 8; ++mt) {
      #pragma unroll
      for (int r = 0; r < 4; ++r) {
        int m = m0 + mt*16 + kg*4 + r;
        int s = m >> 4, b = m & 15;
        float e = (v < NV) ? (acc[mt][nt][r] + pb) : 0.f;
        if (e == 0.f) e = NEG_INF;
        outp[((long)b*NTT + s)*NEXT + v] = e;
      }
    }
  }
}

// ---------------- copy-scatter compose ----------------
__device__ __forceinline__ float dec_f(unsigned e) {
  return (e & 0x80000000u) ? __uint_as_float(e ^ 0x80000000u) : __uint_as_float(~e);
}
__global__ __launch_bounds__(512) void k_compose_all(
    const int* __restrict__ ids, const float* __restrict__ coveAll,
    unsigned* __restrict__ ubuf, float* __restrict__ outp)
{
  int b = blockIdx.x, tid = threadIdx.x;
  int v = 0;
  if (tid < TSN) v = ids[b*TSN + tid];
  unsigned* up = ubuf + (long)b*NEXT;
  for (int s = 0; s < NTT; ++s) {
    if (tid < TSN) {
      float ce = coveAll[((long)s*NB + b)*TSN + tid];
      unsigned bb = __float_as_uint(ce);
      unsigned enc = (bb & 0x80000000u) ? ~bb : (bb | 0x80000000u);
      atomicMax(&up[v], enc);
    }
    __syncthreads();
    if (tid < TSN) {
      unsigned u = __hip_atomic_load(&up[v], __ATOMIC_RELAXED, __HIP_MEMORY_SCOPE_AGENT);
      float o = dec_f(u);
      long oi = ((long)b*NTT + s)*NEXT + v;
      float e = outp[oi];
      if (e == NEG_INF) e = 0.f;
      float lg = e + o;
      if (lg == 0.f) lg = NEG_INF;
      outp[oi] = lg;
    }
    __syncthreads();
    if (tid < TSN)
      __hip_atomic_store(&up[v], 0u, __ATOMIC_RELAXED, __HIP_MEMORY_SCOPE_AGENT);
    __syncthreads();
  }
}

// ---------------- final coverage-loss scalar ----------------
__global__ void k_covout(const float* __restrict__ covacc, float* __restrict__ outp)
{
  outp[(long)NB*NTT*NEXT] = covacc[0] * (1.0f/(NB*NTT));
}

// ==================== host ====================
extern "C" void kernel_launch(void* const* d_in, const int* in_sizes, int n_in,
                              void* d_out, int out_size, void* d_ws, size_t ws_size,
                              hipStream_t stream) {
  (void)in_sizes; (void)n_in; (void)out_size; (void)ws_size;
  const float* enc_emb = (const float*)d_in[0];
  const float* ans_emb = (const float*)d_in[1];
  const float* dec_emb = (const float*)d_in[2];
  const float* eWi0 = (const float*)d_in[3];
  const float* eWh0 = (const float*)d_in[4];
  const float* ebi0 = (const float*)d_in[5];
  const float* ebh0 = (const float*)d_in[6];
  const float* eWi1 = (const float*)d_in[7];
  const float* eWh1 = (const float*)d_in[8];
  const float* ebi1 = (const float*)d_in[9];
  const float* ebh1 = (const float*)d_in[10];
  const float* trans_W = (const float*)d_in[11];
  const float* trans_b = (const float*)d_in[12];
  const float* upd_W = (const float*)d_in[13];
  const float* gate_W = (const float*)d_in[14];
  const float* dWi0 = (const float*)d_in[15];
  const float* dWh0 = (const float*)d_in[16];
  const float* dbi0 = (const float*)d_in[17];
  const float* dbh0 = (const float*)d_in[18];
  const float* dWi1 = (const float*)d_in[19];
  const float* dWh1 = (const float*)d_in[20];
  const float* dbi1 = (const float*)d_in[21];
  const float* dbh1 = (const float*)d_in[22];
  const float* dtrans_W = (const float*)d_in[23];
  const float* dtrans_b = (const float*)d_in[24];
  const float* pW1 = (const float*)d_in[25];
  const float* pb1 = (const float*)d_in[26];
  const float* pW2 = (const float*)d_in[27];
  const float* pb2 = (const float*)d_in[28];
  const int* input_s = (const int*)d_in[29];
  const int* ext_ids = (const int*)d_in[30];
  const int* input_q = (const int*)d_in[31];
  const int* input_a = (const int*)d_in[32];
  float* out = (float*)d_out;

  float* ws = (float*)d_ws;
  size_t off = 0;
  auto alloc = [&](size_t n) { float* p = ws + off; off += (n + 15) & ~(size_t)15; return p; };
  auto alloch = [&](size_t nh) { return (ushort*)alloc((nh + 1) / 2); };

  // --- small persistent ---
  ushort* hpp  = alloch(2ull*2*NB*HENC);
  int*   bar   = (int*)alloc(2048);   // 2 layers x [2 dir][8][32] ints
  float* covacc= alloc(4);
  float* cov   = alloc(NB*TSN);
  unsigned* ubuf = (unsigned*)alloc((size_t)NB*NEXT);
  float* hfin0 = alloc(NB*HD2);
  float* hfin1 = alloc(NB*HD2);
  float* dh0   = alloc(2ull*NB*HD2);
  float* dh1   = alloc(2ull*NB*HD2);
  ushort* h0b  = alloch(2ull*NB*HD2);
  ushort* h1b  = alloch(2ull*NB*HD2);
  ushort* ctxbf= alloch(2ull*NB*HD2);
  ushort* catbf= alloch((size_t)NB*2048);
  ushort* hidAll = alloch((size_t)NTT*NB*HD2);   // [32][16][1024]
  float* coveAll = alloc((size_t)NTT*NB*TSN);    // [32][16][400]

  // --- bf16 weights ---
  ushort* eWi0c   = alloch(2ull*G3E*384);
  ushort* eWi1c   = alloch(2ull*G3E*1024);
  ushort* Whb0    = alloch(2ull*G3E*HENC);
  ushort* Whb1    = alloch(2ull*G3E*HENC);
  ushort* transWb = alloch(1024ull*1024);
  ushort* updWb   = alloch(1024ull*2048);
  ushort* gateWb  = alloch(1024ull*2048);
  ushort* dtransWb= alloch(1024ull*1024);
  ushort* dWi0e   = alloch(3072ull*320);
  ushort* dWi0c   = alloch(3072ull*1024);
  ushort* dWh0b   = alloch(3072ull*1024);
  ushort* dWi1b   = alloch(3072ull*1024);
  ushort* dWh1b   = alloch(3072ull*1024);
  ushort* pW1b    = alloch(1024ull*2048);

  // --- alias region: [GX | X0c | Y0bf | ft] reused later as pW2b (+outpTb) ---
  size_t regionStart = off;
  float*  GX   = alloc(2ull*6400*G3E);
  ushort* X0c  = alloch(6400ull*384);
  ushort* Y0bf = alloch(6400ull*1024);
  float*  ft   = alloc(6400ull*HD2);
  ushort* pW2b   = (ushort*)(ws + regionStart);
  ushort* outpTb = (ushort*)(ws + regionStart + 26000000);

  // --- big buffers ---
  ushort* outpbf = alloch(6400ull*HD2);
  ushort* memsbf = alloch(6400ull*HD2);
  float*  scratchC = alloc(6400ull*HD2);
  float*  energ  = alloc((size_t)NB*TSN*TSN);
  ushort* scoresb= alloch((size_t)NB*TSN*448);
  ushort* ctx_bf = alloch(6400ull*HD2);
  ushort* memd_bf= alloch(6400ull*HD2);
  ushort* encbf  = alloch(6400ull*HD2);
  ushort* embqb  = alloch(512ull*320);
  float*  embGX  = alloc(512ull*G3D);

  // ---------------- one-time casts ----------------
  k_embed_bf<<<9600, 256, 0, stream>>>(enc_emb, ans_emb, input_s, input_a, X0c);
  k_castw<<<4608, 256, 0, stream>>>(eWi0, eWi0c, 3072, 3072ull*384, 332, 384, 332, 0);
  k_castw<<<12288, 256, 0, stream>>>(eWi1, eWi1c, 3072, 3072ull*1024, 1024, 1024, 1024, 0);
  k_castw<<<6144, 256, 0, stream>>>(eWh0, Whb0, 3072, 3072ull*512, 512, 512, 512, 0);
  k_castw<<<6144, 256, 0, stream>>>(eWh1, Whb1, 3072, 3072ull*512, 512, 512, 512, 0);
  k_castw<<<4096, 256, 0, stream>>>(trans_W, transWb, 1024, 1024ull*1024, 1024, 1024, 1024, 0);
  k_castw<<<8192, 256, 0, stream>>>(upd_W,  updWb,  1024, 1024ull*2048, 2048, 2048, 2048, 0);
  k_castw<<<8192, 256, 0, stream>>>(gate_W, gateWb, 1024, 1024ull*2048, 2048, 2048, 2048, 0);
  k_castw<<<4096, 256, 0, stream>>>(dtrans_W, dtransWb, 1024, 1024ull*1024, 1024, 1024, 1024, 0);
  k_castw<<<3840, 256, 0, stream>>>(dWi0, dWi0e, 3072, 3072ull*320, 300, 320, 1324, 0);
  k_castw<<<12288, 256, 0, stream>>>(dWi0, dWi0c, 3072, 3072ull*1024, 1024, 1024, 1324, 300);
  k_castw<<<12288, 256, 0, stream>>>(dWh0, dWh0b, 3072, 3072ull*1024, 1024, 1024, 1024, 0);
  k_castw<<<12288, 256, 0, stream>>>(dWi1, dWi1b, 3072, 3072ull*1024, 1024, 1024, 1024, 0);
  k_castw<<<12288, 256, 0, stream>>>(dWh1, dWh1b, 3072, 3072ull*1024, 1024, 1024, 1024, 0);
  k_castw<<<8192, 256, 0, stream>>>(pW1, pW1b, 1024, 1024ull*2048, 2048, 2048, 2048, 0);

  hipMemsetAsync(bar, 0, 8192, stream);

  // ---------------- encoder layer 0 ----------------
  k_mfma_nt<<<dim3(100,24,2), 256, 0, stream>>>(X0c, eWi0c, ebi0, GX, nullptr,
      6400, G3E, 384, 384, 384, G3E, 0, (long)G3E*384, 6400ull*G3E, G3E, 0, 0);
  hipMemsetAsync(hpp, 0, 2ull*2*NB*HENC*2, stream);
  k_scan_mfma<<<16, 512, 0, stream>>>(GX, GX + 6400ull*G3E, Whb0, ebh0,
      Y0bf, 0, hfin0, hpp, bar);
  // ---------------- encoder layer 1 ----------------
  k_mfma_nt<<<dim3(100,24,2), 256, 0, stream>>>(Y0bf, eWi1c, ebi1, GX, nullptr,
      6400, G3E, 1024, 1024, 1024, G3E, 0, (long)G3E*1024, 6400ull*G3E, G3E, 0, 0);
  hipMemsetAsync(hpp, 0, 2ull*2*NB*HENC*2, stream);
  k_scan_mfma<<<16, 512, 0, stream>>>(GX, GX + 6400ull*G3E, Whb1, ebh1,
      outpbf, 1, hfin1, hpp, bar + 512);

  // ---------------- self/answer attention ----------------
  k_mfma_nt<<<dim3(100,16,1), 256, 0, stream>>>(outpbf, transWb, trans_b, scratchC, memsbf,
      6400, HD2, 1024, 1024, 1024, HD2, 0, 0, 0, 0, 0, 0);
  k_mfma_nt<<<dim3(7,7,16), 256, 0, stream>>>(outpbf, memsbf, nullptr, energ, nullptr,
      TSN, TSN, 1024, 1024, 1024, TSN, (long)TSN*1024, (long)TSN*1024, (long)TSN*TSN, 0, 0, 0);
  k_softmax_bf<<<NB*TSN, 256, 0, stream>>>(energ, scoresb);
  k_transpose_hh<<<dim3(14,32,16), 256, 0, stream>>>(outpbf, outpTb);
  k_mfma_nt<<<dim3(7,16,16), 256, 0, stream>>>(scoresb, outpTb, nullptr, scratchC, ctx_bf,
      TSN, HD2, 448, 448, 448, HD2, (long)TSN*448, (long)HD2*448, (long)TSN*HD2, 0, 0, 0);
  k_mfma_nt<<<dim3(100,16,1), 256, 0, stream>>>(outpbf, updWb,        nullptr, ft, nullptr,
      6400, HD2, 1024, 1024, 2048, HD2, 0, 0, 0, 0, 0, 0);
  k_mfma_nt<<<dim3(100,16,1), 256, 0, stream>>>(ctx_bf, updWb + 1024, nullptr, ft, nullptr,
      6400, HD2, 1024, 1024, 2048, HD2, 0, 0, 0, 0, 1, 1);
  k_mfma_nt<<<dim3(100,16,1), 256, 0, stream>>>(outpbf, gateWb,       nullptr, scratchC, nullptr,
      6400, HD2, 1024, 1024, 2048, HD2, 0, 0, 0, 0, 0, 0);
  k_mfma_nt<<<dim3(100,16,1), 256, 0, stream>>>(ctx_bf, gateWb + 1024, nullptr, scratchC, nullptr,
      6400, HD2, 1024, 1024, 2048, HD2, 0, 0, 0, 0, 1, 2);
  k_ansatt2<<<64, 256, 0, stream>>>(memsbf, ft, scratchC, outpbf, input_a, encbf);
  // region now dead: cast pW2
  k_castw<<<200704, 256, 0, stream>>>(pW2, pW2b, NV, (long)NVP*1024, 1024, 1024, 1024, 0);
  k_mfma_nt<<<dim3(100,16,1), 256, 0, stream>>>(encbf, dtransWb, dtrans_b, scratchC, memd_bf,
      6400, HD2, 1024, 1024, 1024, HD2, 0, 0, 0, 0, 0, 0);

  // ---------------- decoder precompute ----------------
  k_embq_bf<<<640, 256, 0, stream>>>(dec_emb, input_q, embqb);
  k_mfma_nt<<<dim3(8,48,1), 256, 0, stream>>>(embqb, dWi0e, dbi0, embGX, nullptr,
      NTT*NB, G3D, 320, 320, 320, G3D, 0, 0, 0, 0, 0, 0);

  hipMemsetAsync(cov, 0, (size_t)NB*TSN*4, stream);
  hipMemsetAsync(covacc, 0, 4, stream);
  hipMemsetAsync(ubuf, 0, (size_t)NB*NEXT*4, stream);
  hipMemsetAsync(ctxbf, 0, (size_t)NB*HD2*2, stream);
  hipMemcpyAsync(dh0, hfin0, (size_t)NB*HD2*4, hipMemcpyDeviceToDevice, stream);
  hipMemcpyAsync(dh1, hfin1, (size_t)NB*HD2*4, hipMemcpyDeviceToDevice, stream);
  k_cast<<<64, 256, 0, stream>>>(hfin0, h0b, 16384);
  k_cast<<<64, 256, 0, stream>>>(hfin1, h1b, 16384);

  // ---------------- decoder steps (no logits in loop) ----------------
  for (int s = 0; s < NTT; ++s) {
    int cur = s & 1, nxt = cur ^ 1;
    float* h0c = dh0 + (size_t)cur*NB*HD2;  float* h0n = dh0 + (size_t)nxt*NB*HD2;
    float* h1c = dh1 + (size_t)cur*NB*HD2;  float* h1n = dh1 + (size_t)nxt*NB*HD2;
    ushort* h0bc = h0b + (size_t)cur*NB*HD2; ushort* h0bn = h0b + (size_t)nxt*NB*HD2;
    ushort* h1bc = h1b + (size_t)cur*NB*HD2; ushort* h1bn = h1b + (size_t)nxt*NB*HD2;
    ushort* ctxc = ctxbf + (size_t)cur*NB*HD2; ushort* ctxn = ctxbf + (size_t)nxt*NB*HD2;

    k_gru_dec<<<64, 64, 0, stream>>>(ctxc, dWi0c, h0bc, dWh0b,
        embGX + (size_t)s*NB*G3D, nullptr, dbh0, h0c, h0n, h0bn, nullptr);
    k_gru_dec<<<64, 64, 0, stream>>>(h0bn, dWi1b, h1bc, dWh1b,
        nullptr, dbi1, dbh1, h1c, h1n, h1bn, catbf);
    k_dec_attn2<<<NB, 1024, 0, stream>>>(h1bn, memd_bf,
        cov, coveAll + (size_t)s*NB*TSN, covacc, ctxn, catbf);
    k_hid<<<64, 64, 0, stream>>>(catbf, pW1b, pb1, hidAll + (size_t)s*NB*HD2);
  }
  // ---------------- batched logits + compose ----------------
  k_logits_all<<<dim3(196, 4), 256, 0, stream>>>(hidAll, pW2b, pb2, out);
  k_compose_all<<<NB, 512, 0, stream>>>(ext_ids, coveAll, ubuf, out);
  k_covout<<<1, 1, 0, stream>>>(covacc, out);
}

// Round 9
// 6137.980 us; speedup vs baseline: 1.2975x; 1.1258x over previous
//
#include <hip/hip_runtime.h>
#include <stdint.h>

#define TSN 400
#define NB 16
#define HENC 512
#define HD2 1024
#define G3E 1536
#define G3D 3072
#define EMBD 300
#define AEMB 32
#define NV 50000
#define NEXT 50100
#define NVP 50176
#define NTT 32
#define NEG_INF (-1.0e12f)

typedef __attribute__((ext_vector_type(8))) short bf16x8;
typedef __attribute__((ext_vector_type(4))) float f32x4;

__device__ __forceinline__ ushort f2bf(float f) {
  unsigned u = __float_as_uint(f);
  unsigned r = (u + 0x7fffu + ((u >> 16) & 1u)) >> 16;
  return (ushort)r;
}
__device__ __forceinline__ float bf2f(ushort h) {
  return __uint_as_float((unsigned)h << 16);
}
__device__ __forceinline__ unsigned agat_ld(const unsigned* p) {
  return __hip_atomic_load(p, __ATOMIC_RELAXED, __HIP_MEMORY_SCOPE_AGENT);
}
__device__ __forceinline__ void agat_st(unsigned* p, unsigned v) {
  __hip_atomic_store(p, v, __ATOMIC_RELAXED, __HIP_MEMORY_SCOPE_AGENT);
}

// ---------------- embeddings -> bf16, padded K=384 ----------------
__global__ __launch_bounds__(256) void k_embed_bf(
    const float* __restrict__ enc_emb, const float* __restrict__ ans_emb,
    const int* __restrict__ input_s, const int* __restrict__ input_a,
    ushort* __restrict__ X0)
{
  long i = (long)blockIdx.x*256 + threadIdx.x;
  if (i >= (long)TSN*NB*384) return;
  int c = (int)(i % 384);
  long r = i / 384;
  int b = (int)(r % NB);
  int t = (int)(r / NB);
  float v = 0.f;
  if (c < EMBD) v = enc_emb[(long)input_s[b*TSN + t]*EMBD + c];
  else if (c < 332) v = ans_emb[(long)input_a[b*TSN + t]*AEMB + (c - EMBD)];
  X0[i] = f2bf(v);
}

// ---------------- decoder emb -> bf16, padded K=320 ----------------
__global__ __launch_bounds__(256) void k_embq_bf(
    const float* __restrict__ dec_emb, const int* __restrict__ input_q,
    ushort* __restrict__ EQ)
{
  long i = (long)blockIdx.x*256 + threadIdx.x;
  if (i >= (long)NTT*NB*320) return;
  int c = (int)(i % 320);
  long r = i / 320;
  int b = (int)(r % NB);
  int s = (int)(r / NB);
  EQ[i] = (c < EMBD) ? f2bf(dec_emb[(long)input_q[b*33 + s]*EMBD + c]) : (ushort)0;
}

// ---------------- weight cast with pad ----------------
__global__ __launch_bounds__(256) void k_castw(
    const float* __restrict__ src, ushort* __restrict__ dst,
    int Nsrc, long total, int Ksrc, int Kdst, int ldsrc, int coloff)
{
  long i = (long)blockIdx.x*256 + threadIdx.x;
  if (i >= total) return;
  int k = (int)(i % Kdst);
  long n = i / Kdst;
  float v = (n < Nsrc && k < Ksrc) ? src[n*ldsrc + coloff + k] : 0.f;
  dst[i] = f2bf(v);
}

// ---------------- plain cast fp32 -> bf16 ----------------
__global__ __launch_bounds__(256) void k_cast(
    const float* __restrict__ s, ushort* __restrict__ d, long n)
{
  long i = (long)blockIdx.x*256 + threadIdx.x;
  if (i >= n) return;
  d[i] = f2bf(s[i]);
}

// ---------------- bf16 batched transpose with K-pad: out[b][c][r(448)] ----------------
__global__ __launch_bounds__(256) void k_transpose_hh(
    const ushort* __restrict__ in, ushort* __restrict__ out)
{
  __shared__ ushort tb[32][33];
  int b = blockIdx.z;
  int r0 = blockIdx.x*32, c0 = blockIdx.y*32;
  int tx = threadIdx.x & 31, ty = threadIdx.x >> 5;
  #pragma unroll
  for (int i = 0; i < 32; i += 8) {
    int r = r0 + ty + i, c = c0 + tx;
    tb[ty+i][tx] = (r < TSN) ? in[((long)b*TSN + r)*1024 + c] : (ushort)0;
  }
  __syncthreads();
  #pragma unroll
  for (int i = 0; i < 32; i += 8) {
    int c = c0 + ty + i, r = r0 + tx;
    out[((long)b*1024 + c)*448 + r] = tb[tx][ty+i];
  }
}

// ---------------- MFMA GEMM (fp32 C optional; bf16 C2 optional) ----------------
__global__ __launch_bounds__(256) void k_mfma_nt(
    const ushort* __restrict__ Ab, const ushort* __restrict__ Wb,
    const float* __restrict__ bias, float* __restrict__ Cb, ushort* __restrict__ C2b,
    int M, int N, int K, int lda, int ldw, int ldc,
    long sA, long sW, long sC, long sBias, int accum, int act)
{
  __shared__ ushort As[64][72];
  __shared__ ushort Ws[64][72];
  const ushort* A = Ab + (long)blockIdx.z * sA;
  const ushort* W = Wb + (long)blockIdx.z * sW;
  float* C = Cb ? Cb + (long)blockIdx.z * sC : nullptr;
  const float* bi = bias ? bias + (long)blockIdx.z * sBias : nullptr;
  const int m0 = blockIdx.x*64, n0 = blockIdx.y*64;
  const int tid = threadIdx.x;
  const int wave = tid >> 6, lane = tid & 63;
  const int wm = wave >> 1, wn = wave & 1;
  const int lr = lane & 15, kg = lane >> 4;
  f32x4 acc[2][2] = {};
  for (int k0 = 0; k0 < K; k0 += 64) {
    __syncthreads();
    #pragma unroll
    for (int it = 0; it < 2; ++it) {
      int sidx = tid + it*256;
      int r = sidx >> 3, c = (sidx & 7)*8;
      bf16x8 av = {};
      bf16x8 wv = {};
      if (m0 + r < M) av = *(const bf16x8*)&A[(long)(m0+r)*lda + k0 + c];
      if (n0 + r < N) wv = *(const bf16x8*)&W[(long)(n0+r)*ldw + k0 + c];
      *(bf16x8*)&As[r][c] = av;
      *(bf16x8*)&Ws[r][c] = wv;
    }
    __syncthreads();
    #pragma unroll
    for (int kk = 0; kk < 2; ++kk) {
      bf16x8 af[2], bf[2];
      #pragma unroll
      for (int mt = 0; mt < 2; ++mt)
        af[mt] = *(const bf16x8*)&As[wm*32 + mt*16 + lr][kk*32 + kg*8];
      #pragma unroll
      for (int nt = 0; nt < 2; ++nt)
        bf[nt] = *(const bf16x8*)&Ws[wn*32 + nt*16 + lr][kk*32 + kg*8];
      #pragma unroll
      for (int mt = 0; mt < 2; ++mt)
        #pragma unroll
        for (int nt = 0; nt < 2; ++nt)
          acc[mt][nt] = __builtin_amdgcn_mfma_f32_16x16x32_bf16(af[mt], bf[nt], acc[mt][nt], 0, 0, 0);
    }
  }
  #pragma unroll
  for (int mt = 0; mt < 2; ++mt) {
    #pragma unroll
    for (int r = 0; r < 4; ++r) {
      int m = m0 + wm*32 + mt*16 + kg*4 + r;
      if (m >= M) continue;
      #pragma unroll
      for (int nt = 0; nt < 2; ++nt) {
        int n = n0 + wn*32 + nt*16 + lr;
        if (n >= N) continue;
        float v = acc[mt][nt][r];
        if (accum && C) v += C[(long)m*ldc + n];
        if (bi)    v += bi[n];
        if (act == 1) v = tanhf(v);
        else if (act == 2) v = 1.f/(1.f + expf(-v));
        if (C) C[(long)m*ldc + n] = v;
        if (C2b) C2b[(long)blockIdx.z*sC + (long)m*ldc + n] = f2bf(v);
      }
    }
  }
}

// ---------------- persistent MFMA bidirectional GRU scan v6 ----------------
// v4 structure (16 blocks x 256, 8/dir) + bf16 gx + short drain:
// gx prefetch and Y writes issued AFTER the slot store so vmcnt(0) drains
// only the h-exchange stores; gx HBM latency hides under the poll.
__global__ __launch_bounds__(256, 1) void k_scan_mfma(
    const ushort* __restrict__ GXf, const ushort* __restrict__ GXb,  // bf16 gx
    const ushort* __restrict__ Whb,   // [2][1536][512] bf16
    const float* __restrict__ bh,     // [2][1536]
    ushort* __restrict__ Ybf, int bmajor,
    float* __restrict__ hfin,
    ushort* __restrict__ hpp,         // [2 ping][2 dir][16 b][512 j] bf16
    int* __restrict__ slots)          // [2 dir][8][32] ints
{
  const int bid = blockIdx.x;
  const int tid = threadIdx.x;
  const int wg = bid*4 + (tid >> 6);
  const int lane = tid & 63;
  const int lr = lane & 15, kg = lane >> 4;
  const int dir = wg >> 5, jt = wg & 31;
  const int j = jt*16 + lr;
  __shared__ ushort hsm[16][520];
  const ushort* Wp0 = Whb + ((long)(dir*G3E + j)        << 9) + kg*8;
  const ushort* Wp1 = Whb + ((long)(dir*G3E + 512 + j)  << 9) + kg*8;
  const ushort* Wp2 = Whb + ((long)(dir*G3E + 1024 + j) << 9) + kg*8;
  bf16x8 W0[16], W1[16], W2[16];
  #pragma unroll
  for (int i = 0; i < 16; ++i) {
    W0[i] = *(const bf16x8*)(Wp0 + i*32);
    W1[i] = *(const bf16x8*)(Wp1 + i*32);
    W2[i] = *(const bf16x8*)(Wp2 + i*32);
  }
  const float bh0 = bh[dir*G3E + j];
  const float bh1 = bh[dir*G3E + 512 + j];
  const float bh2 = bh[dir*G3E + 1024 + j];
  const ushort* GX = dir ? GXb : GXf;
  unsigned* hppu = (unsigned*)hpp;
  int* myslot = slots + dir*256 + (bid & 7)*32;
  int* dslots = slots + dir*256;
  float hreg[4] = {0.f, 0.f, 0.f, 0.f};
  float g0[4], g1[4], g2[4];
  {
    const int t0 = dir ? (TSN - 1) : 0;
    const ushort* gxp = GX + (long)t0*NB*G3E + j;
    #pragma unroll
    for (int r = 0; r < 4; ++r) {
      const ushort* g = gxp + (long)(kg*4 + r)*G3E;
      g0[r] = bf2f(g[0]); g1[r] = bf2f(g[512]); g2[r] = bf2f(g[1024]);
    }
  }
  for (int s = 0; s < TSN; ++s) {
    const int cur = s & 1;
    // ---- coalesced agent-atomic load of full h(dir) -> LDS ----
    {
      const unsigned* hin = hppu + (cur*2 + dir)*4096;
      unsigned vdw[16];
      #pragma unroll
      for (int i = 0; i < 16; ++i) vdw[i] = agat_ld(hin + i*256 + tid);
      #pragma unroll
      for (int i = 0; i < 16; ++i) {
        int idx = i*256 + tid;
        int b = idx >> 8, jd = idx & 255;
        *(unsigned*)&hsm[b][jd*2] = vdw[i];
      }
    }
    __syncthreads();
    f32x4 a0 = {}, a1 = {}, a2 = {};
    #pragma unroll
    for (int i = 0; i < 16; ++i) {
      bf16x8 hf = *(const bf16x8*)&hsm[lr][kg*8 + i*32];
      a0 = __builtin_amdgcn_mfma_f32_16x16x32_bf16(hf, W0[i], a0, 0, 0, 0);
      a1 = __builtin_amdgcn_mfma_f32_16x16x32_bf16(hf, W1[i], a1, 0, 0, 0);
      a2 = __builtin_amdgcn_mfma_f32_16x16x32_bf16(hf, W2[i], a2, 0, 0, 0);
    }
    const int t = dir ? (TSN - 1 - s) : s;
    const int obase = ((cur^1)*2 + dir)*16*512;
    float hsave[4];
    #pragma unroll
    for (int r = 0; r < 4; ++r) {
      int b = kg*4 + r;
      float rr = 1.f/(1.f + expf(-(g0[r] + a0[r] + bh0)));
      float zz = 1.f/(1.f + expf(-(g1[r] + a1[r] + bh1)));
      float nn = tanhf(g2[r] + rr*(a2[r] + bh2));
      float hn = (1.f - zz)*nn + zz*hreg[r];
      hreg[r] = hn;
      hsave[r] = hn;
      unsigned hv = f2bf(hn);
      unsigned pv = (unsigned)__shfl_xor((int)hv, 1);
      if ((lr & 1) == 0)
        agat_st(hppu + ((obase + b*512 + j) >> 1), hv | (pv << 16));
    }
    if (s + 1 < TSN) {
      // drain ONLY the h-exchange stores, then signal
      asm volatile("s_waitcnt vmcnt(0)" ::: "memory");
      __syncthreads();
      if (tid == 0)
        agat_st((unsigned*)myslot, (unsigned)(s + 1));
      // issue next gx prefetch + Y writes; they overlap the poll
      {
        const int tn = dir ? (TSN - 2 - s) : (s + 1);
        const ushort* gxp = GX + (long)tn*NB*G3E + j;
        #pragma unroll
        for (int r = 0; r < 4; ++r) {
          const ushort* g = gxp + (long)(kg*4 + r)*G3E;
          g0[r] = bf2f(g[0]); g1[r] = bf2f(g[512]); g2[r] = bf2f(g[1024]);
        }
      }
      #pragma unroll
      for (int r = 0; r < 4; ++r) {
        int b = kg*4 + r;
        long yi = bmajor ? ((long)b*TSN + t)*1024 + dir*512 + j
                         : ((long)t*NB + b)*1024 + dir*512 + j;
        Ybf[yi] = f2bf(hsave[r]);
      }
      if (tid < 8) {
        while ((int)agat_ld((const unsigned*)(dslots + tid*32)) < s + 1)
          __builtin_amdgcn_s_sleep(1);
      }
      __syncthreads();
    } else {
      #pragma unroll
      for (int r = 0; r < 4; ++r) {
        int b = kg*4 + r;
        long yi = bmajor ? ((long)b*TSN + t)*1024 + dir*512 + j
                         : ((long)t*NB + b)*1024 + dir*512 + j;
        Ybf[yi] = f2bf(hsave[r]);
        hfin[b*1024 + dir*512 + j] = hsave[r];
      }
    }
  }
}

// ---------------- row softmax f32 -> bf16 (pad to 448) ----------------
__global__ __launch_bounds__(256) void k_softmax_bf(
    const float* __restrict__ E, ushort* __restrict__ S)
{
  long row = blockIdx.x;
  const float* x = E + row*TSN;
  ushort* o = S + row*448;
  int tid = threadIdx.x;
  float v0 = (tid < TSN) ? x[tid] : -INFINITY;
  float v1 = (tid + 256 < TSN) ? x[tid + 256] : -INFINITY;
  __shared__ float red[256];
  red[tid] = fmaxf(v0, v1); __syncthreads();
  for (int oo = 128; oo; oo >>= 1) { if (tid < oo) red[tid] = fmaxf(red[tid], red[tid+oo]); __syncthreads(); }
  float m = red[0]; __syncthreads();
  float e0 = (tid < TSN) ? expf(v0 - m) : 0.f;
  float e1 = (tid + 256 < TSN) ? expf(v1 - m) : 0.f;
  red[tid] = e0 + e1; __syncthreads();
  for (int oo = 128; oo; oo >>= 1) { if (tid < oo) red[tid] += red[tid+oo]; __syncthreads(); }
  float inv = 1.f/red[0];
  if (tid < 192) o[tid + 256] = (tid + 256 < TSN) ? f2bf(e1*inv) : (ushort)0;
  o[tid] = f2bf(e0*inv);
}

// ---------------- fused selfcomb + answer attention -> encbf ----------------
__global__ __launch_bounds__(256) void k_ansatt2(
    const ushort* __restrict__ memsb, const float* __restrict__ ft,
    const float* __restrict__ gt, const ushort* __restrict__ outpb,
    const int* __restrict__ input_a, ushort* __restrict__ encb)
{
  int b = blockIdx.x >> 2;
  int d = (blockIdx.x & 3)*256 + threadIdx.x;
  __shared__ int ia[TSN];
  for (int i = threadIdx.x; i < TSN; i += 256) ia[i] = input_a[b*TSN + i];
  __syncthreads();
  float m = -INFINITY;
  #pragma unroll 4
  for (int t = 0; t < TSN; ++t) {
    float v = bf2f(memsb[((long)b*TSN + t)*1024 + d]);
    float e = ia[t] ? v*v : v;
    m = fmaxf(m, e);
  }
  float ssum = 0.f;
  #pragma unroll 4
  for (int t = 0; t < TSN; ++t) {
    float v = bf2f(memsb[((long)b*TSN + t)*1024 + d]);
    float e = ia[t] ? v*v : v;
    ssum += expf(e - m);
  }
  float inv = 1.f/ssum;
  #pragma unroll 4
  for (int t = 0; t < TSN; ++t) {
    long idx = ((long)b*TSN + t)*1024 + d;
    float v = bf2f(memsb[idx]);
    float e = ia[t] ? v*v : v;
    float gg = gt[idx];
    float selfo = gg*ft[idx] + (1.f - gg)*bf2f(outpb[idx]);
    encb[idx] = f2bf(selfo + expf(e - m)*inv*v);
  }
}

// ---------------- decoder GRU layer: 64 blocks x 128 (2 waves split K) ----------------
__global__ __launch_bounds__(128) void k_gru_dec(
    const ushort* __restrict__ A1, const ushort* __restrict__ W1,
    const ushort* __restrict__ A2, const ushort* __restrict__ W2,
    const float* __restrict__ gxadd, const float* __restrict__ bi,
    const float* __restrict__ bh,
    const float* __restrict__ hprev, float* __restrict__ hout,
    ushort* __restrict__ houtb, ushort* __restrict__ catb)
{
  const int wv = threadIdx.x >> 6;
  const int lane = threadIdx.x & 63;
  const int lr = lane & 15, kg = lane >> 4;
  const int j = blockIdx.x*16 + lr;
  const int kb = wv*512;
  __shared__ float psum[6][16][16];
  const ushort* w1p0 = W1 + ((long)(j)        << 10) + kb + kg*8;
  const ushort* w1p1 = W1 + ((long)(1024 + j) << 10) + kb + kg*8;
  const ushort* w1p2 = W1 + ((long)(2048 + j) << 10) + kb + kg*8;
  const ushort* w2p0 = W2 + ((long)(j)        << 10) + kb + kg*8;
  const ushort* w2p1 = W2 + ((long)(1024 + j) << 10) + kb + kg*8;
  const ushort* w2p2 = W2 + ((long)(2048 + j) << 10) + kb + kg*8;
  const ushort* a1p = A1 + lr*1024 + kb + kg*8;
  const ushort* a2p = A2 + lr*1024 + kb + kg*8;
  f32x4 x0 = {}, x1 = {}, x2 = {}, h0 = {}, h1 = {}, h2 = {};
  #pragma unroll 4
  for (int k0 = 0; k0 < 512; k0 += 32) {
    bf16x8 a1v = *(const bf16x8*)(a1p + k0);
    bf16x8 a2v = *(const bf16x8*)(a2p + k0);
    x0 = __builtin_amdgcn_mfma_f32_16x16x32_bf16(a1v, *(const bf16x8*)(w1p0 + k0), x0, 0, 0, 0);
    x1 = __builtin_amdgcn_mfma_f32_16x16x32_bf16(a1v, *(const bf16x8*)(w1p1 + k0), x1, 0, 0, 0);
    x2 = __builtin_amdgcn_mfma_f32_16x16x32_bf16(a1v, *(const bf16x8*)(w1p2 + k0), x2, 0, 0, 0);
    h0 = __builtin_amdgcn_mfma_f32_16x16x32_bf16(a2v, *(const bf16x8*)(w2p0 + k0), h0, 0, 0, 0);
    h1 = __builtin_amdgcn_mfma_f32_16x16x32_bf16(a2v, *(const bf16x8*)(w2p1 + k0), h1, 0, 0, 0);
    h2 = __builtin_amdgcn_mfma_f32_16x16x32_bf16(a2v, *(const bf16x8*)(w2p2 + k0), h2, 0, 0, 0);
  }
  if (wv == 1) {
    #pragma unroll
    for (int r = 0; r < 4; ++r) {
      int b = kg*4 + r;
      psum[0][b][lr] = x0[r]; psum[1][b][lr] = x1[r]; psum[2][b][lr] = x2[r];
      psum[3][b][lr] = h0[r]; psum[4][b][lr] = h1[r]; psum[5][b][lr] = h2[r];
    }
  }
  __syncthreads();
  if (wv == 0) {
    float bi0 = bi ? bi[j] : 0.f, bi1 = bi ? bi[1024 + j] : 0.f, bi2 = bi ? bi[2048 + j] : 0.f;
    float bh0 = bh[j], bh1 = bh[1024 + j], bh2 = bh[2048 + j];
    #pragma unroll
    for (int r = 0; r < 4; ++r) {
      int b = kg*4 + r;
      float gxa0 = gxadd ? gxadd[(long)b*G3D + j]        : 0.f;
      float gxa1 = gxadd ? gxadd[(long)b*G3D + 1024 + j] : 0.f;
      float gxa2 = gxadd ? gxadd[(long)b*G3D + 2048 + j] : 0.f;
      float gx0 = x0[r] + psum[0][b][lr] + gxa0 + bi0;
      float gx1 = x1[r] + psum[1][b][lr] + gxa1 + bi1;
      float gx2 = x2[r] + psum[2][b][lr] + gxa2 + bi2;
      float gh0 = h0[r] + psum[3][b][lr] + bh0;
      float gh1 = h1[r] + psum[4][b][lr] + bh1;
      float gh2 = h2[r] + psum[5][b][lr] + bh2;
      float rr = 1.f/(1.f + expf(-(gx0 + gh0)));
      float zz = 1.f/(1.f + expf(-(gx1 + gh1)));
      float nn = tanhf(gx2 + rr*gh2);
      float hp = hprev[b*1024 + j];
      float hn = (1.f - zz)*nn + zz*hp;
      hout[b*1024 + j] = hn;
      houtb[b*1024 + j] = f2bf(hn);
      if (catb) catb[(long)b*2048 + j] = f2bf(hn);
    }
  }
}

// ---------------- fused decoder attention ----------------
__global__ __launch_bounds__(1024) void k_dec_attn2(
    const ushort* __restrict__ h1b, const ushort* __restrict__ memdb,
    float* __restrict__ cov, float* __restrict__ covOut, float* __restrict__ covacc,
    ushort* __restrict__ ctxn, ushort* __restrict__ catb)
{
  const int b = blockIdx.x, tid = threadIdx.x;
  const int wv = tid >> 6, ln = tid & 63;
  __shared__ float sc[TSN];
  __shared__ float at[TSN];
  __shared__ float red[1024];
  float hreg[16];
  {
    bf16x8 hv0 = *(const bf16x8*)&h1b[b*1024 + ln*16];
    bf16x8 hv1 = *(const bf16x8*)&h1b[b*1024 + ln*16 + 8];
    #pragma unroll
    for (int e = 0; e < 8; ++e) { hreg[e] = bf2f((ushort)hv0[e]); hreg[8+e] = bf2f((ushort)hv1[e]); }
  }
  for (int t = wv; t < TSN; t += 16) {
    const ushort* row = memdb + ((long)b*TSN + t)*1024 + ln*16;
    bf16x8 r0 = *(const bf16x8*)row;
    bf16x8 r1 = *(const bf16x8*)(row + 8);
    float p = 0.f;
    #pragma unroll
    for (int e = 0; e < 8; ++e) p += hreg[e]*bf2f((ushort)r0[e]) + hreg[8+e]*bf2f((ushort)r1[e]);
    #pragma unroll
    for (int off = 32; off; off >>= 1) p += __shfl_xor(p, off);
    if (ln == 0) sc[t] = p;
  }
  __syncthreads();
  float ce = -INFINITY, co = 0.f;
  if (tid < TSN) { co = cov[b*TSN + tid]; ce = sc[tid]*(1.f - co); }
  red[tid] = ce; __syncthreads();
  for (int o = 512; o; o >>= 1) { if (tid < o) red[tid] = fmaxf(red[tid], red[tid+o]); __syncthreads(); }
  float m = red[0]; __syncthreads();
  float ex = (tid < TSN) ? expf(ce - m) : 0.f;
  red[tid] = ex; __syncthreads();
  for (int o = 512; o; o >>= 1) { if (tid < o) red[tid] += red[tid+o]; __syncthreads(); }
  float inv = 1.f/red[0]; __syncthreads();
  float closs = 0.f;
  if (tid < TSN) {
    float a = ex*inv;
    at[tid] = a;
    cov[b*TSN + tid] = co + a;
    covOut[b*TSN + tid] = ce;
    closs = fminf(a, co);
  }
  red[tid] = closs; __syncthreads();
  for (int o = 512; o; o >>= 1) { if (tid < o) red[tid] += red[tid+o]; __syncthreads(); }
  if (tid == 0) atomicAdd(covacc, red[0]);
  __syncthreads();
  float s = 0.f;
  const ushort* col = memdb + (long)b*TSN*1024 + tid;
  #pragma unroll 8
  for (int t = 0; t < TSN; ++t) s += at[t]*bf2f(col[(long)t*1024]);
  ushort hv = f2bf(s);
  ctxn[b*1024 + tid] = hv;
  catb[(long)b*2048 + 1024 + tid] = hv;
}

// ---------------- hid = tanh(cat @ pW1^T + pb1): 64 blocks x 128 (2 waves split K) ----------------
__global__ __launch_bounds__(128) void k_hid(
    const ushort* __restrict__ catb, const ushort* __restrict__ W,
    const float* __restrict__ pb1, ushort* __restrict__ hidb)
{
  const int wv = threadIdx.x >> 6;
  const int lane = threadIdx.x & 63;
  const int lr = lane & 15, kg = lane >> 4;
  const int n = blockIdx.x*16 + lr;
  const int kb = wv*1024;
  __shared__ float ps[16][16];
  f32x4 acc = {};
  const ushort* ap = catb + lr*2048 + kb + kg*8;
  const ushort* wp = W + ((long)n << 11) + kb + kg*8;
  #pragma unroll 8
  for (int k0 = 0; k0 < 1024; k0 += 32)
    acc = __builtin_amdgcn_mfma_f32_16x16x32_bf16(*(const bf16x8*)(ap + k0), *(const bf16x8*)(wp + k0), acc, 0, 0, 0);
  if (wv == 1) {
    #pragma unroll
    for (int r = 0; r < 4; ++r) ps[kg*4 + r][lr] = acc[r];
  }
  __syncthreads();
  if (wv == 0) {
    float bv = pb1[n];
    #pragma unroll
    for (int r = 0; r < 4; ++r) {
      int b = kg*4 + r;
      hidb[b*1024 + n] = f2bf(tanhf(acc[r] + ps[b][lr] + bv));
    }
  }
}

// ---------------- batched logits ----------------
__global__ __launch_bounds__(256) void k_logits_all(
    const ushort* __restrict__ hidAll,
    const ushort* __restrict__ pW2b,
    const float* __restrict__ pb2,
    float* __restrict__ outp)
{
  const int wave = threadIdx.x >> 6, lane = threadIdx.x & 63;
  const int lr = lane & 15, kg = lane >> 4;
  const int n0 = blockIdx.x*256 + wave*64;
  const int m0 = blockIdx.y*128;
  f32x4 acc[8][4] = {};
  for (int k0 = 0; k0 < 1024; k0 += 32) {
    bf16x8 bfr[4];
    #pragma unroll
    for (int nt = 0; nt < 4; ++nt)
      bfr[nt] = *(const bf16x8*)&pW2b[(long)(n0 + nt*16 + lr)*1024 + k0 + kg*8];
    #pragma unroll
    for (int mt = 0; mt < 8; ++mt) {
      bf16x8 af = *(const bf16x8*)&hidAll[(long)(m0 + mt*16 + lr)*1024 + k0 + kg*8];
      #pragma unroll
      for (int nt = 0; nt < 4; ++nt)
        acc[mt][nt] = __builtin_amdgcn_mfma_f32_16x16x32_bf16(af, bfr[nt], acc[mt][nt], 0, 0, 0);
    }
  }
  #pragma unroll
  for (int nt = 0; nt < 4; ++nt) {
    int v = n0 + nt*16 + lr;
    if (v >= NEXT) continue;
    float pb = (v < NV) ? pb2[v] : 0.f;
    #pragma unroll
    for (int mt = 0; mt < 8; ++mt) {
      #pragma unroll
      for (int r = 0; r < 4; ++r) {
        int m = m0 + mt*16 + kg*4 + r;
        int s = m >> 4, b = m & 15;
        float e = (v < NV) ? (acc[mt][nt][r] + pb) : 0.f;
        if (e == 0.f) e = NEG_INF;
        outp[((long)b*NTT + s)*NEXT + v] = e;
      }
    }
  }
}

// ---------------- copy-scatter compose ----------------
__device__ __forceinline__ float dec_f(unsigned e) {
  return (e & 0x80000000u) ? __uint_as_float(e ^ 0x80000000u) : __uint_as_float(~e);
}
__global__ __launch_bounds__(512) void k_compose_all(
    const int* __restrict__ ids, const float* __restrict__ coveAll,
    unsigned* __restrict__ ubuf, float* __restrict__ outp)
{
  int b = blockIdx.x, tid = threadIdx.x;
  int v = 0;
  if (tid < TSN) v = ids[b*TSN + tid];
  unsigned* up = ubuf + (long)b*NEXT;
  for (int s = 0; s < NTT; ++s) {
    if (tid < TSN) {
      float ce = coveAll[((long)s*NB + b)*TSN + tid];
      unsigned bb = __float_as_uint(ce);
      unsigned enc = (bb & 0x80000000u) ? ~bb : (bb | 0x80000000u);
      atomicMax(&up[v], enc);
    }
    __syncthreads();
    if (tid < TSN) {
      unsigned u = __hip_atomic_load(&up[v], __ATOMIC_RELAXED, __HIP_MEMORY_SCOPE_AGENT);
      float o = dec_f(u);
      long oi = ((long)b*NTT + s)*NEXT + v;
      float e = outp[oi];
      if (e == NEG_INF) e = 0.f;
      float lg = e + o;
      if (lg == 0.f) lg = NEG_INF;
      outp[oi] = lg;
    }
    __syncthreads();
    if (tid < TSN)
      __hip_atomic_store(&up[v], 0u, __ATOMIC_RELAXED, __HIP_MEMORY_SCOPE_AGENT);
    __syncthreads();
  }
}

// ---------------- final coverage-loss scalar ----------------
__global__ void k_covout(const float* __restrict__ covacc, float* __restrict__ outp)
{
  outp[(long)NB*NTT*NEXT] = covacc[0] * (1.0f/(NB*NTT));
}

// ==================== host ====================
extern "C" void kernel_launch(void* const* d_in, const int* in_sizes, int n_in,
                              void* d_out, int out_size, void* d_ws, size_t ws_size,
                              hipStream_t stream) {
  (void)in_sizes; (void)n_in; (void)out_size; (void)ws_size;
  const float* enc_emb = (const float*)d_in[0];
  const float* ans_emb = (const float*)d_in[1];
  const float* dec_emb = (const float*)d_in[2];
  const float* eWi0 = (const float*)d_in[3];
  const float* eWh0 = (const float*)d_in[4];
  const float* ebi0 = (const float*)d_in[5];
  const float* ebh0 = (const float*)d_in[6];
  const float* eWi1 = (const float*)d_in[7];
  const float* eWh1 = (const float*)d_in[8];
  const float* ebi1 = (const float*)d_in[9];
  const float* ebh1 = (const float*)d_in[10];
  const float* trans_W = (const float*)d_in[11];
  const float* trans_b = (const float*)d_in[12];
  const float* upd_W = (const float*)d_in[13];
  const float* gate_W = (const float*)d_in[14];
  const float* dWi0 = (const float*)d_in[15];
  const float* dWh0 = (const float*)d_in[16];
  const float* dbi0 = (const float*)d_in[17];
  const float* dbh0 = (const float*)d_in[18];
  const float* dWi1 = (const float*)d_in[19];
  const float* dWh1 = (const float*)d_in[20];
  const float* dbi1 = (const float*)d_in[21];
  const float* dbh1 = (const float*)d_in[22];
  const float* dtrans_W = (const float*)d_in[23];
  const float* dtrans_b = (const float*)d_in[24];
  const float* pW1 = (const float*)d_in[25];
  const float* pb1 = (const float*)d_in[26];
  const float* pW2 = (const float*)d_in[27];
  const float* pb2 = (const float*)d_in[28];
  const int* input_s = (const int*)d_in[29];
  const int* ext_ids = (const int*)d_in[30];
  const int* input_q = (const int*)d_in[31];
  const int* input_a = (const int*)d_in[32];
  float* out = (float*)d_out;

  float* ws = (float*)d_ws;
  size_t off = 0;
  auto alloc = [&](size_t n) { float* p = ws + off; off += (n + 15) & ~(size_t)15; return p; };
  auto alloch = [&](size_t nh) { return (ushort*)alloc((nh + 1) / 2); };

  // --- small persistent ---
  ushort* hpp  = alloch(2ull*2*NB*HENC);
  int*   bar   = (int*)alloc(2048);   // 2 layers x [2 dir][8][32] ints
  float* covacc= alloc(4);
  float* cov   = alloc(NB*TSN);
  unsigned* ubuf = (unsigned*)alloc((size_t)NB*NEXT);
  float* hfin0 = alloc(NB*HD2);
  float* hfin1 = alloc(NB*HD2);
  float* dh0   = alloc(2ull*NB*HD2);
  float* dh1   = alloc(2ull*NB*HD2);
  ushort* h0b  = alloch(2ull*NB*HD2);
  ushort* h1b  = alloch(2ull*NB*HD2);
  ushort* ctxbf= alloch(2ull*NB*HD2);
  ushort* catbf= alloch((size_t)NB*2048);
  ushort* hidAll = alloch((size_t)NTT*NB*HD2);   // [32][16][1024]
  float* coveAll = alloc((size_t)NTT*NB*TSN);    // [32][16][400]

  // --- bf16 weights ---
  ushort* eWi0c   = alloch(2ull*G3E*384);
  ushort* eWi1c   = alloch(2ull*G3E*1024);
  ushort* Whb0    = alloch(2ull*G3E*HENC);
  ushort* Whb1    = alloch(2ull*G3E*HENC);
  ushort* transWb = alloch(1024ull*1024);
  ushort* updWb   = alloch(1024ull*2048);
  ushort* gateWb  = alloch(1024ull*2048);
  ushort* dtransWb= alloch(1024ull*1024);
  ushort* dWi0e   = alloch(3072ull*320);
  ushort* dWi0c   = alloch(3072ull*1024);
  ushort* dWh0b   = alloch(3072ull*1024);
  ushort* dWi1b   = alloch(3072ull*1024);
  ushort* dWh1b   = alloch(3072ull*1024);
  ushort* pW1b    = alloch(1024ull*2048);

  // --- alias region: [GX(bf16, half used) | X0c | Y0bf | ft] reused later as pW2b ---
  size_t regionStart = off;
  float*  GXr  = alloc(2ull*6400*G3E);          // reservation; used as bf16
  ushort* GXbf = (ushort*)GXr;                  // [2][6400][1536] bf16
  ushort* X0c  = alloch(6400ull*384);
  ushort* Y0bf = alloch(6400ull*1024);
  float*  ft   = alloc(6400ull*HD2);
  ushort* pW2b   = (ushort*)(ws + regionStart);
  ushort* outpTb = (ushort*)(ws + regionStart + 26000000);

  // --- big buffers ---
  ushort* outpbf = alloch(6400ull*HD2);
  ushort* memsbf = alloch(6400ull*HD2);
  float*  scratchC = alloc(6400ull*HD2);
  float*  energ  = alloc((size_t)NB*TSN*TSN);
  ushort* scoresb= alloch((size_t)NB*TSN*448);
  ushort* ctx_bf = alloch(6400ull*HD2);
  ushort* memd_bf= alloch(6400ull*HD2);
  ushort* encbf  = alloch(6400ull*HD2);
  ushort* embqb  = alloch(512ull*320);
  float*  embGX  = alloc(512ull*G3D);

  // ---------------- one-time casts ----------------
  k_embed_bf<<<9600, 256, 0, stream>>>(enc_emb, ans_emb, input_s, input_a, X0c);
  k_castw<<<4608, 256, 0, stream>>>(eWi0, eWi0c, 3072, 3072ull*384, 332, 384, 332, 0);
  k_castw<<<12288, 256, 0, stream>>>(eWi1, eWi1c, 3072, 3072ull*1024, 1024, 1024, 1024, 0);
  k_castw<<<6144, 256, 0, stream>>>(eWh0, Whb0, 3072, 3072ull*512, 512, 512, 512, 0);
  k_castw<<<6144, 256, 0, stream>>>(eWh1, Whb1, 3072, 3072ull*512, 512, 512, 512, 0);
  k_castw<<<4096, 256, 0, stream>>>(trans_W, transWb, 1024, 1024ull*1024, 1024, 1024, 1024, 0);
  k_castw<<<8192, 256, 0, stream>>>(upd_W,  updWb,  1024, 1024ull*2048, 2048, 2048, 2048, 0);
  k_castw<<<8192, 256, 0, stream>>>(gate_W, gateWb, 1024, 1024ull*2048, 2048, 2048, 2048, 0);
  k_castw<<<4096, 256, 0, stream>>>(dtrans_W, dtransWb, 1024, 1024ull*1024, 1024, 1024, 1024, 0);
  k_castw<<<3840, 256, 0, stream>>>(dWi0, dWi0e, 3072, 3072ull*320, 300, 320, 1324, 0);
  k_castw<<<12288, 256, 0, stream>>>(dWi0, dWi0c, 3072, 3072ull*1024, 1024, 1024, 1324, 300);
  k_castw<<<12288, 256, 0, stream>>>(dWh0, dWh0b, 3072, 3072ull*1024, 1024, 1024, 1024, 0);
  k_castw<<<12288, 256, 0, stream>>>(dWi1, dWi1b, 3072, 3072ull*1024, 1024, 1024, 1024, 0);
  k_castw<<<12288, 256, 0, stream>>>(dWh1, dWh1b, 3072, 3072ull*1024, 1024, 1024, 1024, 0);
  k_castw<<<8192, 256, 0, stream>>>(pW1, pW1b, 1024, 1024ull*2048, 2048, 2048, 2048, 0);

  hipMemsetAsync(bar, 0, 8192, stream);

  // ---------------- encoder layer 0 (bf16 gx out) ----------------
  k_mfma_nt<<<dim3(100,24,2), 256, 0, stream>>>(X0c, eWi0c, ebi0, nullptr, GXbf,
      6400, G3E, 384, 384, 384, G3E, 0, (long)G3E*384, 6400ull*G3E, G3E, 0, 0);
  hipMemsetAsync(hpp, 0, 2ull*2*NB*HENC*2, stream);
  k_scan_mfma<<<16, 256, 0, stream>>>(GXbf, GXbf + 6400ull*G3E, Whb0, ebh0,
      Y0bf, 0, hfin0, hpp, bar);
  // ---------------- encoder layer 1 (bf16 gx out) ----------------
  k_mfma_nt<<<dim3(100,24,2), 256, 0, stream>>>(Y0bf, eWi1c, ebi1, nullptr, GXbf,
      6400, G3E, 1024, 1024, 1024, G3E, 0, (long)G3E*1024, 6400ull*G3E, G3E, 0, 0);
  hipMemsetAsync(hpp, 0, 2ull*2*NB*HENC*2, stream);
  k_scan_mfma<<<16, 256, 0, stream>>>(GXbf, GXbf + 6400ull*G3E, Whb1, ebh1,
      outpbf, 1, hfin1, hpp, bar + 512);

  // ---------------- self/answer attention ----------------
  k_mfma_nt<<<dim3(100,16,1), 256, 0, stream>>>(outpbf, transWb, trans_b, scratchC, memsbf,
      6400, HD2, 1024, 1024, 1024, HD2, 0, 0, 0, 0, 0, 0);
  k_mfma_nt<<<dim3(7,7,16), 256, 0, stream>>>(outpbf, memsbf, nullptr, energ, nullptr,
      TSN, TSN, 1024, 1024, 1024, TSN, (long)TSN*1024, (long)TSN*1024, (long)TSN*TSN, 0, 0, 0);
  k_softmax_bf<<<NB*TSN, 256, 0, stream>>>(energ, scoresb);
  k_transpose_hh<<<dim3(14,32,16), 256, 0, stream>>>(outpbf, outpTb);
  k_mfma_nt<<<dim3(7,16,16), 256, 0, stream>>>(scoresb, outpTb, nullptr, scratchC, ctx_bf,
      TSN, HD2, 448, 448, 448, HD2, (long)TSN*448, (long)HD2*448, (long)TSN*HD2, 0, 0, 0);
  k_mfma_nt<<<dim3(100,16,1), 256, 0, stream>>>(outpbf, updWb,        nullptr, ft, nullptr,
      6400, HD2, 1024, 1024, 2048, HD2, 0, 0, 0, 0, 0, 0);
  k_mfma_nt<<<dim3(100,16,1), 256, 0, stream>>>(ctx_bf, updWb + 1024, nullptr, ft, nullptr,
      6400, HD2, 1024, 1024, 2048, HD2, 0, 0, 0, 0, 1, 1);
  k_mfma_nt<<<dim3(100,16,1), 256, 0, stream>>>(outpbf, gateWb,       nullptr, scratchC, nullptr,
      6400, HD2, 1024, 1024, 2048, HD2, 0, 0, 0, 0, 0, 0);
  k_mfma_nt<<<dim3(100,16,1), 256, 0, stream>>>(ctx_bf, gateWb + 1024, nullptr, scratchC, nullptr,
      6400, HD2, 1024, 1024, 2048, HD2, 0, 0, 0, 0, 1, 2);
  k_ansatt2<<<64, 256, 0, stream>>>(memsbf, ft, scratchC, outpbf, input_a, encbf);
  // region now dead: cast pW2
  k_castw<<<200704, 256, 0, stream>>>(pW2, pW2b, NV, (long)NVP*1024, 1024, 1024, 1024, 0);
  k_mfma_nt<<<dim3(100,16,1), 256, 0, stream>>>(encbf, dtransWb, dtrans_b, scratchC, memd_bf,
      6400, HD2, 1024, 1024, 1024, HD2, 0, 0, 0, 0, 0, 0);

  // ---------------- decoder precompute ----------------
  k_embq_bf<<<640, 256, 0, stream>>>(dec_emb, input_q, embqb);
  k_mfma_nt<<<dim3(8,48,1), 256, 0, stream>>>(embqb, dWi0e, dbi0, embGX, nullptr,
      NTT*NB, G3D, 320, 320, 320, G3D, 0, 0, 0, 0, 0, 0);

  hipMemsetAsync(cov, 0, (size_t)NB*TSN*4, stream);
  hipMemsetAsync(covacc, 0, 4, stream);
  hipMemsetAsync(ubuf, 0, (size_t)NB*NEXT*4, stream);
  hipMemsetAsync(ctxbf, 0, (size_t)NB*HD2*2, stream);
  hipMemcpyAsync(dh0, hfin0, (size_t)NB*HD2*4, hipMemcpyDeviceToDevice, stream);
  hipMemcpyAsync(dh1, hfin1, (size_t)NB*HD2*4, hipMemcpyDeviceToDevice, stream);
  k_cast<<<64, 256, 0, stream>>>(hfin0, h0b, 16384);
  k_cast<<<64, 256, 0, stream>>>(hfin1, h1b, 16384);

  // ---------------- decoder steps (no logits in loop) ----------------
  for (int s = 0; s < NTT; ++s) {
    int cur = s & 1, nxt = cur ^ 1;
    float* h0c = dh0 + (size_t)cur*NB*HD2;  float* h0n = dh0 + (size_t)nxt*NB*HD2;
    float* h1c = dh1 + (size_t)cur*NB*HD2;  float* h1n = dh1 + (size_t)nxt*NB*HD2;
    ushort* h0bc = h0b + (size_t)cur*NB*HD2; ushort* h0bn = h0b + (size_t)nxt*NB*HD2;
    ushort* h1bc = h1b + (size_t)cur*NB*HD2; ushort* h1bn = h1b + (size_t)nxt*NB*HD2;
    ushort* ctxc = ctxbf + (size_t)cur*NB*HD2; ushort* ctxn = ctxbf + (size_t)nxt*NB*HD2;

    k_gru_dec<<<64, 128, 0, stream>>>(ctxc, dWi0c, h0bc, dWh0b,
        embGX + (size_t)s*NB*G3D, nullptr, dbh0, h0c, h0n, h0bn, nullptr);
    k_gru_dec<<<64, 128, 0, stream>>>(h0bn, dWi1b, h1bc, dWh1b,
        nullptr, dbi1, dbh1, h1c, h1n, h1bn, catbf);
    k_dec_attn2<<<NB, 1024, 0, stream>>>(h1bn, memd_bf,
        cov, coveAll + (size_t)s*NB*TSN, covacc, ctxn, catbf);
    k_hid<<<64, 128, 0, stream>>>(catbf, pW1b, pb1, hidAll + (size_t)s*NB*HD2);
  }
  // ---------------- batched logits + compose ----------------
  k_logits_all<<<dim3(196, 4), 256, 0, stream>>>(hidAll, pW2b, pb2, out);
  k_compose_all<<<NB, 512, 0, stream>>>(ext_ids, coveAll, ubuf, out);
  k_covout<<<1, 1, 0, stream>>>(covacc, out);
}

// Round 10
// 6000.994 us; speedup vs baseline: 1.3271x; 1.0228x over previous
//
#include <hip/hip_runtime.h>
#include <stdint.h>

#define TSN 400
#define NB 16
#define HENC 512
#define HD2 1024
#define G3E 1536
#define G3D 3072
#define EMBD 300
#define AEMB 32
#define NV 50000
#define NEXT 50100
#define NVP 50176
#define NTT 32
#define NEG_INF (-1.0e12f)

typedef __attribute__((ext_vector_type(8))) short bf16x8;
typedef __attribute__((ext_vector_type(4))) float f32x4;

__device__ __forceinline__ ushort f2bf(float f) {
  unsigned u = __float_as_uint(f);
  unsigned r = (u + 0x7fffu + ((u >> 16) & 1u)) >> 16;
  return (ushort)r;
}
__device__ __forceinline__ float bf2f(ushort h) {
  return __uint_as_float((unsigned)h << 16);
}
__device__ __forceinline__ unsigned agat_ld(const unsigned* p) {
  return __hip_atomic_load(p, __ATOMIC_RELAXED, __HIP_MEMORY_SCOPE_AGENT);
}
__device__ __forceinline__ void agat_st(unsigned* p, unsigned v) {
  __hip_atomic_store(p, v, __ATOMIC_RELAXED, __HIP_MEMORY_SCOPE_AGENT);
}

// ---------------- embeddings -> bf16, padded K=384 ----------------
__global__ __launch_bounds__(256) void k_embed_bf(
    const float* __restrict__ enc_emb, const float* __restrict__ ans_emb,
    const int* __restrict__ input_s, const int* __restrict__ input_a,
    ushort* __restrict__ X0)
{
  long i = (long)blockIdx.x*256 + threadIdx.x;
  if (i >= (long)TSN*NB*384) return;
  int c = (int)(i % 384);
  long r = i / 384;
  int b = (int)(r % NB);
  int t = (int)(r / NB);
  float v = 0.f;
  if (c < EMBD) v = enc_emb[(long)input_s[b*TSN + t]*EMBD + c];
  else if (c < 332) v = ans_emb[(long)input_a[b*TSN + t]*AEMB + (c - EMBD)];
  X0[i] = f2bf(v);
}

// ---------------- decoder emb -> bf16, padded K=320 ----------------
__global__ __launch_bounds__(256) void k_embq_bf(
    const float* __restrict__ dec_emb, const int* __restrict__ input_q,
    ushort* __restrict__ EQ)
{
  long i = (long)blockIdx.x*256 + threadIdx.x;
  if (i >= (long)NTT*NB*320) return;
  int c = (int)(i % 320);
  long r = i / 320;
  int b = (int)(r % NB);
  int s = (int)(r / NB);
  EQ[i] = (c < EMBD) ? f2bf(dec_emb[(long)input_q[b*33 + s]*EMBD + c]) : (ushort)0;
}

// ---------------- weight cast with pad ----------------
__global__ __launch_bounds__(256) void k_castw(
    const float* __restrict__ src, ushort* __restrict__ dst,
    int Nsrc, long total, int Ksrc, int Kdst, int ldsrc, int coloff)
{
  long i = (long)blockIdx.x*256 + threadIdx.x;
  if (i >= total) return;
  int k = (int)(i % Kdst);
  long n = i / Kdst;
  float v = (n < Nsrc && k < Ksrc) ? src[n*ldsrc + coloff + k] : 0.f;
  dst[i] = f2bf(v);
}

// ---------------- plain cast fp32 -> bf16 ----------------
__global__ __launch_bounds__(256) void k_cast(
    const float* __restrict__ s, ushort* __restrict__ d, long n)
{
  long i = (long)blockIdx.x*256 + threadIdx.x;
  if (i >= n) return;
  d[i] = f2bf(s[i]);
}

// ---------------- copy bf16 [6400][1024] -> catE[:, :1024] (stride 2048) ----------------
__global__ __launch_bounds__(256) void k_catcopy(
    const unsigned* __restrict__ src, unsigned* __restrict__ dst)
{
  long i = (long)blockIdx.x*256 + threadIdx.x;   // dword index, 6400*512
  if (i >= 6400l*512) return;
  long r = i >> 9;
  int c = (int)(i & 511);
  dst[(r << 10) + c] = src[i];
}

// ---------------- bf16 batched transpose with K-pad: out[b][c][r(448)] ----------------
__global__ __launch_bounds__(256) void k_transpose_hh(
    const ushort* __restrict__ in, ushort* __restrict__ out)
{
  __shared__ ushort tb[32][33];
  int b = blockIdx.z;
  int r0 = blockIdx.x*32, c0 = blockIdx.y*32;
  int tx = threadIdx.x & 31, ty = threadIdx.x >> 5;
  #pragma unroll
  for (int i = 0; i < 32; i += 8) {
    int r = r0 + ty + i, c = c0 + tx;
    tb[ty+i][tx] = (r < TSN) ? in[((long)b*TSN + r)*1024 + c] : (ushort)0;
  }
  __syncthreads();
  #pragma unroll
  for (int i = 0; i < 32; i += 8) {
    int c = c0 + ty + i, r = r0 + tx;
    out[((long)b*1024 + c)*448 + r] = tb[tx][ty+i];
  }
}

// ---------------- MFMA GEMM (fp32 C optional; bf16 C2 optional) ----------------
__global__ __launch_bounds__(256) void k_mfma_nt(
    const ushort* __restrict__ Ab, const ushort* __restrict__ Wb,
    const float* __restrict__ bias, float* __restrict__ Cb, ushort* __restrict__ C2b,
    int M, int N, int K, int lda, int ldw, int ldc,
    long sA, long sW, long sC, long sBias, int accum, int act)
{
  __shared__ ushort As[64][72];
  __shared__ ushort Ws[64][72];
  const ushort* A = Ab + (long)blockIdx.z * sA;
  const ushort* W = Wb + (long)blockIdx.z * sW;
  float* C = Cb ? Cb + (long)blockIdx.z * sC : nullptr;
  const float* bi = bias ? bias + (long)blockIdx.z * sBias : nullptr;
  const int m0 = blockIdx.x*64, n0 = blockIdx.y*64;
  const int tid = threadIdx.x;
  const int wave = tid >> 6, lane = tid & 63;
  const int wm = wave >> 1, wn = wave & 1;
  const int lr = lane & 15, kg = lane >> 4;
  f32x4 acc[2][2] = {};
  for (int k0 = 0; k0 < K; k0 += 64) {
    __syncthreads();
    #pragma unroll
    for (int it = 0; it < 2; ++it) {
      int sidx = tid + it*256;
      int r = sidx >> 3, c = (sidx & 7)*8;
      bf16x8 av = {};
      bf16x8 wv = {};
      if (m0 + r < M) av = *(const bf16x8*)&A[(long)(m0+r)*lda + k0 + c];
      if (n0 + r < N) wv = *(const bf16x8*)&W[(long)(n0+r)*ldw + k0 + c];
      *(bf16x8*)&As[r][c] = av;
      *(bf16x8*)&Ws[r][c] = wv;
    }
    __syncthreads();
    #pragma unroll
    for (int kk = 0; kk < 2; ++kk) {
      bf16x8 af[2], bf[2];
      #pragma unroll
      for (int mt = 0; mt < 2; ++mt)
        af[mt] = *(const bf16x8*)&As[wm*32 + mt*16 + lr][kk*32 + kg*8];
      #pragma unroll
      for (int nt = 0; nt < 2; ++nt)
        bf[nt] = *(const bf16x8*)&Ws[wn*32 + nt*16 + lr][kk*32 + kg*8];
      #pragma unroll
      for (int mt = 0; mt < 2; ++mt)
        #pragma unroll
        for (int nt = 0; nt < 2; ++nt)
          acc[mt][nt] = __builtin_amdgcn_mfma_f32_16x16x32_bf16(af[mt], bf[nt], acc[mt][nt], 0, 0, 0);
    }
  }
  #pragma unroll
  for (int mt = 0; mt < 2; ++mt) {
    #pragma unroll
    for (int r = 0; r < 4; ++r) {
      int m = m0 + wm*32 + mt*16 + kg*4 + r;
      if (m >= M) continue;
      #pragma unroll
      for (int nt = 0; nt < 2; ++nt) {
        int n = n0 + wn*32 + nt*16 + lr;
        if (n >= N) continue;
        float v = acc[mt][nt][r];
        if (accum && C) v += C[(long)m*ldc + n];
        if (bi)    v += bi[n];
        if (act == 1) v = tanhf(v);
        else if (act == 2) v = 1.f/(1.f + expf(-v));
        if (C) C[(long)m*ldc + n] = v;
        if (C2b) C2b[(long)blockIdx.z*sC + (long)m*ldc + n] = f2bf(v);
      }
    }
  }
}

// ---------------- persistent MFMA bidirectional GRU scan v6 (proven) ----------------
__global__ __launch_bounds__(256, 1) void k_scan_mfma(
    const ushort* __restrict__ GXf, const ushort* __restrict__ GXb,
    const ushort* __restrict__ Whb,
    const float* __restrict__ bh,
    ushort* __restrict__ Ybf, int bmajor,
    float* __restrict__ hfin,
    ushort* __restrict__ hpp,
    int* __restrict__ slots)
{
  const int bid = blockIdx.x;
  const int tid = threadIdx.x;
  const int wg = bid*4 + (tid >> 6);
  const int lane = tid & 63;
  const int lr = lane & 15, kg = lane >> 4;
  const int dir = wg >> 5, jt = wg & 31;
  const int j = jt*16 + lr;
  __shared__ ushort hsm[16][520];
  const ushort* Wp0 = Whb + ((long)(dir*G3E + j)        << 9) + kg*8;
  const ushort* Wp1 = Whb + ((long)(dir*G3E + 512 + j)  << 9) + kg*8;
  const ushort* Wp2 = Whb + ((long)(dir*G3E + 1024 + j) << 9) + kg*8;
  bf16x8 W0[16], W1[16], W2[16];
  #pragma unroll
  for (int i = 0; i < 16; ++i) {
    W0[i] = *(const bf16x8*)(Wp0 + i*32);
    W1[i] = *(const bf16x8*)(Wp1 + i*32);
    W2[i] = *(const bf16x8*)(Wp2 + i*32);
  }
  const float bh0 = bh[dir*G3E + j];
  const float bh1 = bh[dir*G3E + 512 + j];
  const float bh2 = bh[dir*G3E + 1024 + j];
  const ushort* GX = dir ? GXb : GXf;
  unsigned* hppu = (unsigned*)hpp;
  int* myslot = slots + dir*256 + (bid & 7)*32;
  int* dslots = slots + dir*256;
  float hreg[4] = {0.f, 0.f, 0.f, 0.f};
  float g0[4], g1[4], g2[4];
  {
    const int t0 = dir ? (TSN - 1) : 0;
    const ushort* gxp = GX + (long)t0*NB*G3E + j;
    #pragma unroll
    for (int r = 0; r < 4; ++r) {
      const ushort* g = gxp + (long)(kg*4 + r)*G3E;
      g0[r] = bf2f(g[0]); g1[r] = bf2f(g[512]); g2[r] = bf2f(g[1024]);
    }
  }
  for (int s = 0; s < TSN; ++s) {
    const int cur = s & 1;
    {
      const unsigned* hin = hppu + (cur*2 + dir)*4096;
      unsigned vdw[16];
      #pragma unroll
      for (int i = 0; i < 16; ++i) vdw[i] = agat_ld(hin + i*256 + tid);
      #pragma unroll
      for (int i = 0; i < 16; ++i) {
        int idx = i*256 + tid;
        int b = idx >> 8, jd = idx & 255;
        *(unsigned*)&hsm[b][jd*2] = vdw[i];
      }
    }
    __syncthreads();
    f32x4 a0 = {}, a1 = {}, a2 = {};
    #pragma unroll
    for (int i = 0; i < 16; ++i) {
      bf16x8 hf = *(const bf16x8*)&hsm[lr][kg*8 + i*32];
      a0 = __builtin_amdgcn_mfma_f32_16x16x32_bf16(hf, W0[i], a0, 0, 0, 0);
      a1 = __builtin_amdgcn_mfma_f32_16x16x32_bf16(hf, W1[i], a1, 0, 0, 0);
      a2 = __builtin_amdgcn_mfma_f32_16x16x32_bf16(hf, W2[i], a2, 0, 0, 0);
    }
    const int t = dir ? (TSN - 1 - s) : s;
    const int obase = ((cur^1)*2 + dir)*16*512;
    float hsave[4];
    #pragma unroll
    for (int r = 0; r < 4; ++r) {
      int b = kg*4 + r;
      float rr = 1.f/(1.f + expf(-(g0[r] + a0[r] + bh0)));
      float zz = 1.f/(1.f + expf(-(g1[r] + a1[r] + bh1)));
      float nn = tanhf(g2[r] + rr*(a2[r] + bh2));
      float hn = (1.f - zz)*nn + zz*hreg[r];
      hreg[r] = hn;
      hsave[r] = hn;
      unsigned hv = f2bf(hn);
      unsigned pv = (unsigned)__shfl_xor((int)hv, 1);
      if ((lr & 1) == 0)
        agat_st(hppu + ((obase + b*512 + j) >> 1), hv | (pv << 16));
    }
    if (s + 1 < TSN) {
      asm volatile("s_waitcnt vmcnt(0)" ::: "memory");
      __syncthreads();
      if (tid == 0)
        agat_st((unsigned*)myslot, (unsigned)(s + 1));
      {
        const int tn = dir ? (TSN - 2 - s) : (s + 1);
        const ushort* gxp = GX + (long)tn*NB*G3E + j;
        #pragma unroll
        for (int r = 0; r < 4; ++r) {
          const ushort* g = gxp + (long)(kg*4 + r)*G3E;
          g0[r] = bf2f(g[0]); g1[r] = bf2f(g[512]); g2[r] = bf2f(g[1024]);
        }
      }
      #pragma unroll
      for (int r = 0; r < 4; ++r) {
        int b = kg*4 + r;
        long yi = bmajor ? ((long)b*TSN + t)*1024 + dir*512 + j
                         : ((long)t*NB + b)*1024 + dir*512 + j;
        Ybf[yi] = f2bf(hsave[r]);
      }
      if (tid < 8) {
        while ((int)agat_ld((const unsigned*)(dslots + tid*32)) < s + 1)
          __builtin_amdgcn_s_sleep(1);
      }
      __syncthreads();
    } else {
      #pragma unroll
      for (int r = 0; r < 4; ++r) {
        int b = kg*4 + r;
        long yi = bmajor ? ((long)b*TSN + t)*1024 + dir*512 + j
                         : ((long)t*NB + b)*1024 + dir*512 + j;
        Ybf[yi] = f2bf(hsave[r]);
        hfin[b*1024 + dir*512 + j] = hsave[r];
      }
    }
  }
}

// ---------------- row softmax f32 -> bf16 (pad to 448) ----------------
__global__ __launch_bounds__(256) void k_softmax_bf(
    const float* __restrict__ E, ushort* __restrict__ S)
{
  long row = blockIdx.x;
  const float* x = E + row*TSN;
  ushort* o = S + row*448;
  int tid = threadIdx.x;
  float v0 = (tid < TSN) ? x[tid] : -INFINITY;
  float v1 = (tid + 256 < TSN) ? x[tid + 256] : -INFINITY;
  __shared__ float red[256];
  red[tid] = fmaxf(v0, v1); __syncthreads();
  for (int oo = 128; oo; oo >>= 1) { if (tid < oo) red[tid] = fmaxf(red[tid], red[tid+oo]); __syncthreads(); }
  float m = red[0]; __syncthreads();
  float e0 = (tid < TSN) ? expf(v0 - m) : 0.f;
  float e1 = (tid + 256 < TSN) ? expf(v1 - m) : 0.f;
  red[tid] = e0 + e1; __syncthreads();
  for (int oo = 128; oo; oo >>= 1) { if (tid < oo) red[tid] += red[tid+oo]; __syncthreads(); }
  float inv = 1.f/red[0];
  if (tid < 192) o[tid + 256] = (tid + 256 < TSN) ? f2bf(e1*inv) : (ushort)0;
  o[tid] = f2bf(e0*inv);
}

// ---------------- fused selfcomb (raw preacts) + answer attention -> encbf ----------------
__global__ __launch_bounds__(256) void k_ansatt2(
    const ushort* __restrict__ memsb, const ushort* __restrict__ ftgt,
    const ushort* __restrict__ outpb,
    const int* __restrict__ input_a, ushort* __restrict__ encb)
{
  int b = blockIdx.x >> 2;
  int d = (blockIdx.x & 3)*256 + threadIdx.x;
  __shared__ int ia[TSN];
  for (int i = threadIdx.x; i < TSN; i += 256) ia[i] = input_a[b*TSN + i];
  __syncthreads();
  float m = -INFINITY;
  #pragma unroll 4
  for (int t = 0; t < TSN; ++t) {
    float v = bf2f(memsb[((long)b*TSN + t)*1024 + d]);
    float e = ia[t] ? v*v : v;
    m = fmaxf(m, e);
  }
  float ssum = 0.f;
  #pragma unroll 4
  for (int t = 0; t < TSN; ++t) {
    float v = bf2f(memsb[((long)b*TSN + t)*1024 + d]);
    float e = ia[t] ? v*v : v;
    ssum += expf(e - m);
  }
  float inv = 1.f/ssum;
  #pragma unroll 4
  for (int t = 0; t < TSN; ++t) {
    long idx = ((long)b*TSN + t)*1024 + d;
    long idx2 = ((long)b*TSN + t)*2048 + d;
    float v = bf2f(memsb[idx]);
    float e = ia[t] ? v*v : v;
    float fraw = bf2f(ftgt[idx2]);
    float graw = bf2f(ftgt[idx2 + 1024]);
    float gg = 1.f/(1.f + expf(-graw));
    float selfo = gg*tanhf(fraw) + (1.f - gg)*bf2f(outpb[idx]);
    encb[idx] = f2bf(selfo + expf(e - m)*inv*v);
  }
}

// ---------------- decoder GRU layer: 64 blocks x 128 (2 waves split K) ----------------
__global__ __launch_bounds__(128) void k_gru_dec(
    const ushort* __restrict__ A1, const ushort* __restrict__ W1,
    const ushort* __restrict__ A2, const ushort* __restrict__ W2,
    const float* __restrict__ gxadd, const float* __restrict__ bi,
    const float* __restrict__ bh,
    const float* __restrict__ hprev, float* __restrict__ hout,
    ushort* __restrict__ houtb, ushort* __restrict__ catb)
{
  const int wv = threadIdx.x >> 6;
  const int lane = threadIdx.x & 63;
  const int lr = lane & 15, kg = lane >> 4;
  const int j = blockIdx.x*16 + lr;
  const int kb = wv*512;
  __shared__ float psum[6][16][16];
  const ushort* w1p0 = W1 + ((long)(j)        << 10) + kb + kg*8;
  const ushort* w1p1 = W1 + ((long)(1024 + j) << 10) + kb + kg*8;
  const ushort* w1p2 = W1 + ((long)(2048 + j) << 10) + kb + kg*8;
  const ushort* w2p0 = W2 + ((long)(j)        << 10) + kb + kg*8;
  const ushort* w2p1 = W2 + ((long)(1024 + j) << 10) + kb + kg*8;
  const ushort* w2p2 = W2 + ((long)(2048 + j) << 10) + kb + kg*8;
  const ushort* a1p = A1 + lr*1024 + kb + kg*8;
  const ushort* a2p = A2 + lr*1024 + kb + kg*8;
  f32x4 x0 = {}, x1 = {}, x2 = {}, h0 = {}, h1 = {}, h2 = {};
  #pragma unroll 4
  for (int k0 = 0; k0 < 512; k0 += 32) {
    bf16x8 a1v = *(const bf16x8*)(a1p + k0);
    bf16x8 a2v = *(const bf16x8*)(a2p + k0);
    x0 = __builtin_amdgcn_mfma_f32_16x16x32_bf16(a1v, *(const bf16x8*)(w1p0 + k0), x0, 0, 0, 0);
    x1 = __builtin_amdgcn_mfma_f32_16x16x32_bf16(a1v, *(const bf16x8*)(w1p1 + k0), x1, 0, 0, 0);
    x2 = __builtin_amdgcn_mfma_f32_16x16x32_bf16(a1v, *(const bf16x8*)(w1p2 + k0), x2, 0, 0, 0);
    h0 = __builtin_amdgcn_mfma_f32_16x16x32_bf16(a2v, *(const bf16x8*)(w2p0 + k0), h0, 0, 0, 0);
    h1 = __builtin_amdgcn_mfma_f32_16x16x32_bf16(a2v, *(const bf16x8*)(w2p1 + k0), h1, 0, 0, 0);
    h2 = __builtin_amdgcn_mfma_f32_16x16x32_bf16(a2v, *(const bf16x8*)(w2p2 + k0), h2, 0, 0, 0);
  }
  if (wv == 1) {
    #pragma unroll
    for (int r = 0; r < 4; ++r) {
      int b = kg*4 + r;
      psum[0][b][lr] = x0[r]; psum[1][b][lr] = x1[r]; psum[2][b][lr] = x2[r];
      psum[3][b][lr] = h0[r]; psum[4][b][lr] = h1[r]; psum[5][b][lr] = h2[r];
    }
  }
  __syncthreads();
  if (wv == 0) {
    float bi0 = bi ? bi[j] : 0.f, bi1 = bi ? bi[1024 + j] : 0.f, bi2 = bi ? bi[2048 + j] : 0.f;
    float bh0 = bh[j], bh1 = bh[1024 + j], bh2 = bh[2048 + j];
    #pragma unroll
    for (int r = 0; r < 4; ++r) {
      int b = kg*4 + r;
      float gxa0 = gxadd ? gxadd[(long)b*G3D + j]        : 0.f;
      float gxa1 = gxadd ? gxadd[(long)b*G3D + 1024 + j] : 0.f;
      float gxa2 = gxadd ? gxadd[(long)b*G3D + 2048 + j] : 0.f;
      float gx0 = x0[r] + psum[0][b][lr] + gxa0 + bi0;
      float gx1 = x1[r] + psum[1][b][lr] + gxa1 + bi1;
      float gx2 = x2[r] + psum[2][b][lr] + gxa2 + bi2;
      float gh0 = h0[r] + psum[3][b][lr] + bh0;
      float gh1 = h1[r] + psum[4][b][lr] + bh1;
      float gh2 = h2[r] + psum[5][b][lr] + bh2;
      float rr = 1.f/(1.f + expf(-(gx0 + gh0)));
      float zz = 1.f/(1.f + expf(-(gx1 + gh1)));
      float nn = tanhf(gx2 + rr*gh2);
      float hp = hprev[b*1024 + j];
      float hn = (1.f - zz)*nn + zz*hp;
      hout[b*1024 + j] = hn;
      houtb[b*1024 + j] = f2bf(hn);
      if (catb) catb[(long)b*2048 + j] = f2bf(hn);
    }
  }
}

// ---------------- fused decoder attention v3: 64 blocks, 1 slot barrier ----------------
__global__ __launch_bounds__(256) void k_dec_attn3(
    const ushort* __restrict__ h1b, const ushort* __restrict__ memdb,
    float* __restrict__ cov, float* __restrict__ coveS, float* __restrict__ covacc,
    float* __restrict__ scb,
    ushort* __restrict__ ctxn, ushort* __restrict__ catb,
    int* __restrict__ slots, int epoch)
{
  const int bid = blockIdx.x, tid = threadIdx.x;
  const int b = bid >> 2, q = bid & 3;
  const int wv = tid >> 6, lane = tid & 63;
  __shared__ float at[TSN];
  __shared__ float red[256];
  __shared__ float psD[4][64][4];
  // ---- phase E: energies for t in [q*100, q*100+100) ----
  float hr[16];
  {
    bf16x8 hv0 = *(const bf16x8*)&h1b[b*1024 + lane*16];
    bf16x8 hv1 = *(const bf16x8*)&h1b[b*1024 + lane*16 + 8];
    #pragma unroll
    for (int e = 0; e < 8; ++e) { hr[e] = bf2f((ushort)hv0[e]); hr[8+e] = bf2f((ushort)hv1[e]); }
  }
  #pragma unroll 2
  for (int i = 0; i < 25; ++i) {
    int t = q*100 + wv*25 + i;
    const ushort* row = memdb + ((long)b*TSN + t)*1024 + lane*16;
    bf16x8 r0 = *(const bf16x8*)row;
    bf16x8 r1 = *(const bf16x8*)(row + 8);
    float p = 0.f;
    #pragma unroll
    for (int e = 0; e < 8; ++e) p += hr[e]*bf2f((ushort)r0[e]) + hr[8+e]*bf2f((ushort)r1[e]);
    #pragma unroll
    for (int off = 32; off; off >>= 1) p += __shfl_xor(p, off);
    if (lane == 0) agat_st((unsigned*)&scb[b*TSN + t], __float_as_uint(p));
  }
  // ---- barrier ----
  asm volatile("s_waitcnt vmcnt(0)" ::: "memory");
  __syncthreads();
  if (tid == 0) agat_st((unsigned*)(slots + bid*32), (unsigned)epoch);
  if (tid < 64) {
    while ((int)agat_ld((const unsigned*)(slots + tid*32)) < epoch)
      __builtin_amdgcn_s_sleep(1);
  }
  __syncthreads();
  // ---- phase S: softmax + coverage (redundant per q; q==0 writes) ----
  {
    bool t1v = tid < 144;
    float sc0 = __uint_as_float(agat_ld((const unsigned*)&scb[b*TSN + tid]));
    float sc1 = t1v ? __uint_as_float(agat_ld((const unsigned*)&scb[b*TSN + 256 + tid])) : 0.f;
    float co0 = cov[b*TSN + tid];
    float co1 = t1v ? cov[b*TSN + 256 + tid] : 0.f;
    float ce0 = sc0*(1.f - co0);
    float ce1 = t1v ? sc1*(1.f - co1) : -INFINITY;
    red[tid] = fmaxf(ce0, ce1); __syncthreads();
    for (int o = 128; o; o >>= 1) { if (tid < o) red[tid] = fmaxf(red[tid], red[tid+o]); __syncthreads(); }
    float m = red[0]; __syncthreads();
    float ex0 = expf(ce0 - m), ex1 = t1v ? expf(ce1 - m) : 0.f;
    red[tid] = ex0 + ex1; __syncthreads();
    for (int o = 128; o; o >>= 1) { if (tid < o) red[tid] += red[tid+o]; __syncthreads(); }
    float inv = 1.f/red[0]; __syncthreads();
    float a0 = ex0*inv, a1 = ex1*inv;
    at[tid] = a0;
    if (t1v) at[256 + tid] = a1;
    if (q == 0) {
      coveS[b*TSN + tid] = ce0;
      if (t1v) coveS[b*TSN + 256 + tid] = ce1;
      cov[b*TSN + tid] = co0 + a0;
      if (t1v) cov[b*TSN + 256 + tid] = co1 + a1;
      red[tid] = fminf(a0, co0) + (t1v ? fminf(a1, co1) : 0.f);
      __syncthreads();
      for (int o = 128; o; o >>= 1) { if (tid < o) red[tid] += red[tid+o]; __syncthreads(); }
      if (tid == 0) atomicAdd(covacc, red[0]);
    }
  }
  __syncthreads();
  // ---- phase C: ctx for d in [q*256, q*256+256), wave wv owns 100 t-rows ----
  {
    float acc4[4] = {};
    const int d0 = q*256 + lane*4;
    const unsigned* base = (const unsigned*)memdb + (((long)b*TSN*1024 + d0) >> 1);
    for (int t = wv*100; t < wv*100 + 100; ++t) {
      float a = at[t];
      const unsigned* p = base + (long)t*512;
      unsigned dv0 = p[0], dv1 = p[1];
      acc4[0] += a*bf2f((ushort)(dv0 & 0xffffu));
      acc4[1] += a*bf2f((ushort)(dv0 >> 16));
      acc4[2] += a*bf2f((ushort)(dv1 & 0xffffu));
      acc4[3] += a*bf2f((ushort)(dv1 >> 16));
    }
    #pragma unroll
    for (int e = 0; e < 4; ++e) psD[wv][lane][e] = acc4[e];
    __syncthreads();
    if (wv == 0) {
      float c[4];
      #pragma unroll
      for (int e = 0; e < 4; ++e)
        c[e] = psD[0][lane][e] + psD[1][lane][e] + psD[2][lane][e] + psD[3][lane][e];
      unsigned w0 = (unsigned)f2bf(c[0]) | ((unsigned)f2bf(c[1]) << 16);
      unsigned w1 = (unsigned)f2bf(c[2]) | ((unsigned)f2bf(c[3]) << 16);
      unsigned* cp = (unsigned*)ctxn + ((b*1024 + d0) >> 1);
      cp[0] = w0; cp[1] = w1;
      unsigned* kp = (unsigned*)catb + (((long)b*2048 + 1024 + d0) >> 1);
      kp[0] = w0; kp[1] = w1;
    }
  }
}

// ---------------- hid = tanh(cat @ pW1^T + pb1): 64 blocks x 128 ----------------
__global__ __launch_bounds__(128) void k_hid(
    const ushort* __restrict__ catb, const ushort* __restrict__ W,
    const float* __restrict__ pb1, ushort* __restrict__ hidb)
{
  const int wv = threadIdx.x >> 6;
  const int lane = threadIdx.x & 63;
  const int lr = lane & 15, kg = lane >> 4;
  const int n = blockIdx.x*16 + lr;
  const int kb = wv*1024;
  __shared__ float ps[16][16];
  f32x4 acc = {};
  const ushort* ap = catb + lr*2048 + kb + kg*8;
  const ushort* wp = W + ((long)n << 11) + kb + kg*8;
  #pragma unroll 8
  for (int k0 = 0; k0 < 1024; k0 += 32)
    acc = __builtin_amdgcn_mfma_f32_16x16x32_bf16(*(const bf16x8*)(ap + k0), *(const bf16x8*)(wp + k0), acc, 0, 0, 0);
  if (wv == 1) {
    #pragma unroll
    for (int r = 0; r < 4; ++r) ps[kg*4 + r][lr] = acc[r];
  }
  __syncthreads();
  if (wv == 0) {
    float bv = pb1[n];
    #pragma unroll
    for (int r = 0; r < 4; ++r) {
      int b = kg*4 + r;
      hidb[b*1024 + n] = f2bf(tanhf(acc[r] + ps[b][lr] + bv));
    }
  }
}

// ---------------- batched logits ----------------
__global__ __launch_bounds__(256) void k_logits_all(
    const ushort* __restrict__ hidAll,
    const ushort* __restrict__ pW2b,
    const float* __restrict__ pb2,
    float* __restrict__ outp)
{
  const int wave = threadIdx.x >> 6, lane = threadIdx.x & 63;
  const int lr = lane & 15, kg = lane >> 4;
  const int n0 = blockIdx.x*256 + wave*64;
  const int m0 = blockIdx.y*128;
  f32x4 acc[8][4] = {};
  for (int k0 = 0; k0 < 1024; k0 += 32) {
    bf16x8 bfr[4];
    #pragma unroll
    for (int nt = 0; nt < 4; ++nt)
      bfr[nt] = *(const bf16x8*)&pW2b[(long)(n0 + nt*16 + lr)*1024 + k0 + kg*8];
    #pragma unroll
    for (int mt = 0; mt < 8; ++mt) {
      bf16x8 af = *(const bf16x8*)&hidAll[(long)(m0 + mt*16 + lr)*1024 + k0 + kg*8];
      #pragma unroll
      for (int nt = 0; nt < 4; ++nt)
        acc[mt][nt] = __builtin_amdgcn_mfma_f32_16x16x32_bf16(af, bfr[nt], acc[mt][nt], 0, 0, 0);
    }
  }
  #pragma unroll
  for (int nt = 0; nt < 4; ++nt) {
    int v = n0 + nt*16 + lr;
    if (v >= NEXT) continue;
    float pb = (v < NV) ? pb2[v] : 0.f;
    #pragma unroll
    for (int mt = 0; mt < 8; ++mt) {
      #pragma unroll
      for (int r = 0; r < 4; ++r) {
        int m = m0 + mt*16 + kg*4 + r;
        int s = m >> 4, b = m & 15;
        float e = (v < NV) ? (acc[mt][nt][r] + pb) : 0.f;
        if (e == 0.f) e = NEG_INF;
        outp[((long)b*NTT + s)*NEXT + v] = e;
      }
    }
  }
}

// ---------------- copy-scatter compose ----------------
__device__ __forceinline__ float dec_f(unsigned e) {
  return (e & 0x80000000u) ? __uint_as_float(e ^ 0x80000000u) : __uint_as_float(~e);
}
__global__ __launch_bounds__(512) void k_compose_all(
    const int* __restrict__ ids, const float* __restrict__ coveAll,
    unsigned* __restrict__ ubuf, float* __restrict__ outp)
{
  int b = blockIdx.x, tid = threadIdx.x;
  int v = 0;
  if (tid < TSN) v = ids[b*TSN + tid];
  unsigned* up = ubuf + (long)b*NEXT;
  for (int s = 0; s < NTT; ++s) {
    if (tid < TSN) {
      float ce = coveAll[((long)s*NB + b)*TSN + tid];
      unsigned bb = __float_as_uint(ce);
      unsigned enc = (bb & 0x80000000u) ? ~bb : (bb | 0x80000000u);
      atomicMax(&up[v], enc);
    }
    __syncthreads();
    if (tid < TSN) {
      unsigned u = __hip_atomic_load(&up[v], __ATOMIC_RELAXED, __HIP_MEMORY_SCOPE_AGENT);
      float o = dec_f(u);
      long oi = ((long)b*NTT + s)*NEXT + v;
      float e = outp[oi];
      if (e == NEG_INF) e = 0.f;
      float lg = e + o;
      if (lg == 0.f) lg = NEG_INF;
      outp[oi] = lg;
    }
    __syncthreads();
    if (tid < TSN)
      __hip_atomic_store(&up[v], 0u, __ATOMIC_RELAXED, __HIP_MEMORY_SCOPE_AGENT);
    __syncthreads();
  }
}

// ---------------- final coverage-loss scalar ----------------
__global__ void k_covout(const float* __restrict__ covacc, float* __restrict__ outp)
{
  outp[(long)NB*NTT*NEXT] = covacc[0] * (1.0f/(NB*NTT));
}

// ==================== host ====================
extern "C" void kernel_launch(void* const* d_in, const int* in_sizes, int n_in,
                              void* d_out, int out_size, void* d_ws, size_t ws_size,
                              hipStream_t stream) {
  (void)in_sizes; (void)n_in; (void)out_size; (void)ws_size;
  const float* enc_emb = (const float*)d_in[0];
  const float* ans_emb = (const float*)d_in[1];
  const float* dec_emb = (const float*)d_in[2];
  const float* eWi0 = (const float*)d_in[3];
  const float* eWh0 = (const float*)d_in[4];
  const float* ebi0 = (const float*)d_in[5];
  const float* ebh0 = (const float*)d_in[6];
  const float* eWi1 = (const float*)d_in[7];
  const float* eWh1 = (const float*)d_in[8];
  const float* ebi1 = (const float*)d_in[9];
  const float* ebh1 = (const float*)d_in[10];
  const float* trans_W = (const float*)d_in[11];
  const float* trans_b = (const float*)d_in[12];
  const float* upd_W = (const float*)d_in[13];
  const float* gate_W = (const float*)d_in[14];
  const float* dWi0 = (const float*)d_in[15];
  const float* dWh0 = (const float*)d_in[16];
  const float* dbi0 = (const float*)d_in[17];
  const float* dbh0 = (const float*)d_in[18];
  const float* dWi1 = (const float*)d_in[19];
  const float* dWh1 = (const float*)d_in[20];
  const float* dbi1 = (const float*)d_in[21];
  const float* dbh1 = (const float*)d_in[22];
  const float* dtrans_W = (const float*)d_in[23];
  const float* dtrans_b = (const float*)d_in[24];
  const float* pW1 = (const float*)d_in[25];
  const float* pb1 = (const float*)d_in[26];
  const float* pW2 = (const float*)d_in[27];
  const float* pb2 = (const float*)d_in[28];
  const int* input_s = (const int*)d_in[29];
  const int* ext_ids = (const int*)d_in[30];
  const int* input_q = (const int*)d_in[31];
  const int* input_a = (const int*)d_in[32];
  float* out = (float*)d_out;

  float* ws = (float*)d_ws;
  size_t off = 0;
  auto alloc = [&](size_t n) { float* p = ws + off; off += (n + 15) & ~(size_t)15; return p; };
  auto alloch = [&](size_t nh) { return (ushort*)alloc((nh + 1) / 2); };

  // --- small persistent ---
  ushort* hpp  = alloch(2ull*2*NB*HENC);
  int*   bar   = (int*)alloc(4096);   // scan L0 [0,512), L1 [512,1024), attn [1024,3072)
  float* covacc= alloc(4);
  float* cov   = alloc(NB*TSN);
  float* scb   = alloc(NB*TSN);
  unsigned* ubuf = (unsigned*)alloc((size_t)NB*NEXT);
  float* hfin0 = alloc(NB*HD2);
  float* hfin1 = alloc(NB*HD2);
  float* dh0   = alloc(2ull*NB*HD2);
  float* dh1   = alloc(2ull*NB*HD2);
  ushort* h0b  = alloch(2ull*NB*HD2);
  ushort* h1b  = alloch(2ull*NB*HD2);
  ushort* ctxbf= alloch(2ull*NB*HD2);
  ushort* catbf= alloch((size_t)NB*2048);
  ushort* hidAll = alloch((size_t)NTT*NB*HD2);
  float* coveAll = alloc((size_t)NTT*NB*TSN);

  // --- bf16 weights ---
  ushort* eWi0c   = alloch(2ull*G3E*384);
  ushort* eWi1c   = alloch(2ull*G3E*1024);
  ushort* Whb0    = alloch(2ull*G3E*HENC);
  ushort* Whb1    = alloch(2ull*G3E*HENC);
  ushort* transWb = alloch(1024ull*1024);
  ushort* fgWb    = alloch(2048ull*2048);    // rows 0-1023 upd_W, 1024-2047 gate_W
  ushort* dtransWb= alloch(1024ull*1024);
  ushort* dWi0e   = alloch(3072ull*320);
  ushort* dWi0c   = alloch(3072ull*1024);
  ushort* dWh0b   = alloch(3072ull*1024);
  ushort* dWi1b   = alloch(3072ull*1024);
  ushort* dWh1b   = alloch(3072ull*1024);
  ushort* pW1b    = alloch(1024ull*2048);

  // --- alias region: [GX(bf16) | X0c | Y0bf | pad] -> later ftgt_bf, then pW2b ---
  size_t regionStart = off;
  float*  GXr  = alloc(2ull*6400*G3E);
  ushort* GXbf = (ushort*)GXr;
  ushort* X0c  = alloch(6400ull*384);
  ushort* Y0bf = alloch(6400ull*1024);
  alloc(6400ull*HD2);   // pad to keep region >= 30.7M floats
  ushort* ftgt_bf = (ushort*)(ws + regionStart);             // [6400][2048] bf16 (6.55M f)
  ushort* pW2b    = (ushort*)(ws + regionStart);             // overwrites ftgt after ansatt2
  ushort* outpTb  = (ushort*)(ws + regionStart + 26000000);  // [16][1024][448]

  // --- big buffers ---
  ushort* outpbf = alloch(6400ull*HD2);
  ushort* memsbf = alloch(6400ull*HD2);
  ushort* catE   = alloch(6400ull*2048);     // [6400][2048] = [outp | ctx]
  float*  energ  = alloc((size_t)NB*TSN*TSN);
  ushort* scoresb= alloch((size_t)NB*TSN*448);
  ushort* memd_bf= alloch(6400ull*HD2);
  ushort* encbf  = alloch(6400ull*HD2);
  ushort* embqb  = alloch(512ull*320);
  float*  embGX  = alloc(512ull*G3D);

  // ---------------- one-time casts ----------------
  k_embed_bf<<<9600, 256, 0, stream>>>(enc_emb, ans_emb, input_s, input_a, X0c);
  k_castw<<<4608, 256, 0, stream>>>(eWi0, eWi0c, 3072, 3072ull*384, 332, 384, 332, 0);
  k_castw<<<12288, 256, 0, stream>>>(eWi1, eWi1c, 3072, 3072ull*1024, 1024, 1024, 1024, 0);
  k_castw<<<6144, 256, 0, stream>>>(eWh0, Whb0, 3072, 3072ull*512, 512, 512, 512, 0);
  k_castw<<<6144, 256, 0, stream>>>(eWh1, Whb1, 3072, 3072ull*512, 512, 512, 512, 0);
  k_castw<<<4096, 256, 0, stream>>>(trans_W, transWb, 1024, 1024ull*1024, 1024, 1024, 1024, 0);
  k_castw<<<8192, 256, 0, stream>>>(upd_W,  fgWb,              1024, 1024ull*2048, 2048, 2048, 2048, 0);
  k_castw<<<8192, 256, 0, stream>>>(gate_W, fgWb + 1024ull*2048, 1024, 1024ull*2048, 2048, 2048, 2048, 0);
  k_castw<<<4096, 256, 0, stream>>>(dtrans_W, dtransWb, 1024, 1024ull*1024, 1024, 1024, 1024, 0);
  k_castw<<<3840, 256, 0, stream>>>(dWi0, dWi0e, 3072, 3072ull*320, 300, 320, 1324, 0);
  k_castw<<<12288, 256, 0, stream>>>(dWi0, dWi0c, 3072, 3072ull*1024, 1024, 1024, 1324, 300);
  k_castw<<<12288, 256, 0, stream>>>(dWh0, dWh0b, 3072, 3072ull*1024, 1024, 1024, 1024, 0);
  k_castw<<<12288, 256, 0, stream>>>(dWi1, dWi1b, 3072, 3072ull*1024, 1024, 1024, 1024, 0);
  k_castw<<<12288, 256, 0, stream>>>(dWh1, dWh1b, 3072, 3072ull*1024, 1024, 1024, 1024, 0);
  k_castw<<<8192, 256, 0, stream>>>(pW1, pW1b, 1024, 1024ull*2048, 2048, 2048, 2048, 0);

  hipMemsetAsync(bar, 0, 16384, stream);

  // ---------------- encoder layer 0 ----------------
  k_mfma_nt<<<dim3(100,24,2), 256, 0, stream>>>(X0c, eWi0c, ebi0, nullptr, GXbf,
      6400, G3E, 384, 384, 384, G3E, 0, (long)G3E*384, 6400ull*G3E, G3E, 0, 0);
  hipMemsetAsync(hpp, 0, 2ull*2*NB*HENC*2, stream);
  k_scan_mfma<<<16, 256, 0, stream>>>(GXbf, GXbf + 6400ull*G3E, Whb0, ebh0,
      Y0bf, 0, hfin0, hpp, bar);
  // ---------------- encoder layer 1 ----------------
  k_mfma_nt<<<dim3(100,24,2), 256, 0, stream>>>(Y0bf, eWi1c, ebi1, nullptr, GXbf,
      6400, G3E, 1024, 1024, 1024, G3E, 0, (long)G3E*1024, 6400ull*G3E, G3E, 0, 0);
  hipMemsetAsync(hpp, 0, 2ull*2*NB*HENC*2, stream);
  k_scan_mfma<<<16, 256, 0, stream>>>(GXbf, GXbf + 6400ull*G3E, Whb1, ebh1,
      outpbf, 1, hfin1, hpp, bar + 512);

  // ---------------- self/answer attention ----------------
  k_mfma_nt<<<dim3(100,16,1), 256, 0, stream>>>(outpbf, transWb, trans_b, nullptr, memsbf,
      6400, HD2, 1024, 1024, 1024, HD2, 0, 0, 0, 0, 0, 0);
  k_mfma_nt<<<dim3(7,7,16), 256, 0, stream>>>(outpbf, memsbf, nullptr, energ, nullptr,
      TSN, TSN, 1024, 1024, 1024, TSN, (long)TSN*1024, (long)TSN*1024, (long)TSN*TSN, 0, 0, 0);
  k_softmax_bf<<<NB*TSN, 256, 0, stream>>>(energ, scoresb);
  k_transpose_hh<<<dim3(14,32,16), 256, 0, stream>>>(outpbf, outpTb);
  // ctx -> catE[:, 1024:2048]
  k_mfma_nt<<<dim3(7,16,16), 256, 0, stream>>>(scoresb, outpTb, nullptr, nullptr, catE + 1024,
      TSN, HD2, 448, 448, 448, 2048, (long)TSN*448, (long)HD2*448, (long)TSN*2048, 0, 0, 0);
  k_catcopy<<<12800, 256, 0, stream>>>((const unsigned*)outpbf, (unsigned*)catE);
  // merged f_t/g_t preacts (raw)
  k_mfma_nt<<<dim3(100,32,1), 256, 0, stream>>>(catE, fgWb, nullptr, nullptr, ftgt_bf,
      6400, 2048, 2048, 2048, 2048, 2048, 0, 0, 0, 0, 0, 0);
  k_ansatt2<<<64, 256, 0, stream>>>(memsbf, ftgt_bf, outpbf, input_a, encbf);
  // region dead after ansatt2: cast pW2 over it
  k_castw<<<200704, 256, 0, stream>>>(pW2, pW2b, NV, (long)NVP*1024, 1024, 1024, 1024, 0);
  k_mfma_nt<<<dim3(100,16,1), 256, 0, stream>>>(encbf, dtransWb, dtrans_b, nullptr, memd_bf,
      6400, HD2, 1024, 1024, 1024, HD2, 0, 0, 0, 0, 0, 0);

  // ---------------- decoder precompute ----------------
  k_embq_bf<<<640, 256, 0, stream>>>(dec_emb, input_q, embqb);
  k_mfma_nt<<<dim3(8,48,1), 256, 0, stream>>>(embqb, dWi0e, dbi0, embGX, nullptr,
      NTT*NB, G3D, 320, 320, 320, G3D, 0, 0, 0, 0, 0, 0);

  hipMemsetAsync(cov, 0, (size_t)NB*TSN*4, stream);
  hipMemsetAsync(covacc, 0, 4, stream);
  hipMemsetAsync(ubuf, 0, (size_t)NB*NEXT*4, stream);
  hipMemsetAsync(ctxbf, 0, (size_t)NB*HD2*2, stream);
  hipMemcpyAsync(dh0, hfin0, (size_t)NB*HD2*4, hipMemcpyDeviceToDevice, stream);
  hipMemcpyAsync(dh1, hfin1, (size_t)NB*HD2*4, hipMemcpyDeviceToDevice, stream);
  k_cast<<<64, 256, 0, stream>>>(hfin0, h0b, 16384);
  k_cast<<<64, 256, 0, stream>>>(hfin1, h1b, 16384);

  // ---------------- decoder steps ----------------
  for (int s = 0; s < NTT; ++s) {
    int cur = s & 1, nxt = cur ^ 1;
    float* h0c = dh0 + (size_t)cur*NB*HD2;  float* h0n = dh0 + (size_t)nxt*NB*HD2;
    float* h1c = dh1 + (size_t)cur*NB*HD2;  float* h1n = dh1 + (size_t)nxt*NB*HD2;
    ushort* h0bc = h0b + (size_t)cur*NB*HD2; ushort* h0bn = h0b + (size_t)nxt*NB*HD2;
    ushort* h1bc = h1b + (size_t)cur*NB*HD2; ushort* h1bn = h1b + (size_t)nxt*NB*HD2;
    ushort* ctxc = ctxbf + (size_t)cur*NB*HD2; ushort* ctxn = ctxbf + (size_t)nxt*NB*HD2;

    k_gru_dec<<<64, 128, 0, stream>>>(ctxc, dWi0c, h0bc, dWh0b,
        embGX + (size_t)s*NB*G3D, nullptr, dbh0, h0c, h0n, h0bn, nullptr);
    k_gru_dec<<<64, 128, 0, stream>>>(h0bn, dWi1b, h1bc, dWh1b,
        nullptr, dbi1, dbh1, h1c, h1n, h1bn, catbf);
    k_dec_attn3<<<64, 256, 0, stream>>>(h1bn, memd_bf,
        cov, coveAll + (size_t)s*NB*TSN, covacc, scb, ctxn, catbf,
        bar + 1024, s + 1);
    k_hid<<<64, 128, 0, stream>>>(catbf, pW1b, pb1, hidAll + (size_t)s*NB*HD2);
  }
  // ---------------- batched logits + compose ----------------
  k_logits_all<<<dim3(196, 4), 256, 0, stream>>>(hidAll, pW2b, pb2, out);
  k_compose_all<<<NB, 512, 0, stream>>>(ext_ids, coveAll, ubuf, out);
  k_covout<<<1, 1, 0, stream>>>(covacc, out);
}